// Round 15
// baseline (176.100 us; speedup 1.0000x reference)
//
#include <hip/hip_runtime.h>
#include <stdint.h>

// Problem constants
constexpr int Ee   = 768;
constexpr int Hh   = 12;
constexpr int Dd   = 64;
constexpr int Tt   = 2048;
constexpr int Bb   = 2;
constexpr int HIDc = 3072;
constexpr int MROWS = Bb * Tt;        // 4096
constexpr int NQKV  = 3 * Hh * Dd;    // 2304

typedef unsigned short u16;
typedef __bf16 bf16;
typedef bf16 bf16x8 __attribute__((ext_vector_type(8)));
typedef float f32x4 __attribute__((ext_vector_type(4)));
typedef float f32x16 __attribute__((ext_vector_type(16)));

__device__ __forceinline__ u16 f2bf(float f) {
  uint32_t u = __builtin_bit_cast(uint32_t, f);
  u += 0x7fffu + ((u >> 16) & 1u);
  return (u16)(u >> 16);
}

__device__ __forceinline__ float bf2f(u16 v) {
  uint32_t u = (uint32_t)v << 16;
  return __builtin_bit_cast(float, u);
}

__device__ __forceinline__ uint32_t cvt_pk_bf16(float lo, float hi) {
  uint32_t r;
  asm("v_cvt_pk_bf16_f32 %0, %1, %2" : "=v"(r) : "v"(lo), "v"(hi));
  return r;
}

__device__ __forceinline__ f32x4 mfma16(bf16x8 a, bf16x8 b, f32x4 c) {
  return __builtin_amdgcn_mfma_f32_16x16x32_bf16(a, b, c, 0, 0, 0);
}

__device__ __forceinline__ f32x16 mfma32(bf16x8 a, bf16x8 b, f32x16 c) {
  return __builtin_amdgcn_mfma_f32_32x32x16_bf16(a, b, c, 0, 0, 0);
}

#define GLOAD_LDS16(gp, lp)                                                            \
  __builtin_amdgcn_global_load_lds((const __attribute__((address_space(1))) void*)(gp),\
                                   (__attribute__((address_space(3))) void*)(lp),      \
                                   16, 0, 0)

// XOR swizzle inside a 128-byte LDS row (attention tiles)
#define KSWZ(row, byte) ((row) * 128 + ((byte) ^ (((row) & 7) << 4)))

// ---------------- fused prep: cvt_x + tr_qkv + tr_w1 + tr_w2 ----------------

__device__ __forceinline__ void tr_body(const float* __restrict__ ip,
                                        u16* __restrict__ op,
                                        int R, int C, int r0, int c0,
                                        float (*t)[33]) {
  const int tx = threadIdx.x & 31, ty = threadIdx.x >> 5;
#pragma unroll
  for (int i = 0; i < 4; ++i)
    t[ty * 4 + i][tx] = ip[(size_t)(r0 + ty * 4 + i) * C + c0 + tx];
  __syncthreads();
#pragma unroll
  for (int i = 0; i < 4; ++i)
    op[(size_t)(c0 + ty * 4 + i) * R + r0 + tx] = f2bf(t[tx][ty * 4 + i]);
}

__global__ __launch_bounds__(256) void prep_kernel(
    const float* __restrict__ x, u16* __restrict__ xb,
    const float* __restrict__ Wq, const float* __restrict__ Wk,
    const float* __restrict__ Wv, u16* __restrict__ wqkvt,
    const float* __restrict__ W1, u16* __restrict__ w1t,
    const float* __restrict__ W2, u16* __restrict__ w2t) {
  __shared__ float t[32][33];
  int bid = blockIdx.x;
  if (bid < 3072) {                 // cvt_x
    const int i = bid * 256 + threadIdx.x;
    const float4 f = *(const float4*)(x + (size_t)i * 4);
    uint2 o;
    u16* po = (u16*)&o;
    po[0] = f2bf(f.x); po[1] = f2bf(f.y); po[2] = f2bf(f.z); po[3] = f2bf(f.w);
    *(uint2*)(xb + (size_t)i * 4) = o;
    return;
  }
  bid -= 3072;
  if (bid < 1728) {                 // tr_qkv
    const int bx = bid & 1;
    const int rest = bid >> 1;
    const int by = rest % 24, z = rest / 24;
    const int which = z / 12, hs = z - which * 12;
    const float* W = (which == 0) ? Wq : (which == 1) ? Wk : Wv;
    tr_body(W + (size_t)hs * Ee * Dd, wqkvt + ((size_t)which * 768 + hs * 64) * Ee,
            Ee, Dd, by * 32, bx * 32, t);
    return;
  }
  bid -= 1728;
  if (bid < 2304) {                 // W1
    const int bx = bid % 96, by = bid / 96;
    tr_body(W1, w1t, Ee, HIDc, by * 32, bx * 32, t);
    return;
  }
  bid -= 2304;
  {                                 // W2
    const int bx = bid % 24, by = bid / 24;
    tr_body(W2, w2t, HIDc, Ee, by * 32, bx * 32, t);
  }
}

// ---------------- GEMM (8-wave): C[M,N] = A[M,K] * Bt[N,K]^T ----------------
// BM=256, BN=128, BK=32; 8 waves (4m x 2n), per-wave 64x64 output.
// 3-slot LDS ring (72KB -> 2 blocks/CU), depth-2 counted prefetch:
//   iter it: stage(it+2 -> slot (it+2)%3) ; ds_read+16 MFMA on slot it%3 ;
//            s_waitcnt vmcnt(3) (tile it+1 landed, it+2 stays in flight) ; s_barrier.
// Hazards: ds_reads complete (lgkmcnt) before barrier arrival -> barrier separates
// slot reads from overwrite; per-wave vmcnt + barrier => all portions landed.
// 64B LDS rows, XOR swizzle sl^=(row>>1)&3 (measured 0 conflicts), inverse in src.
// EPI 0: q/k scatter [B,H,T,D]; V directly as sigma-V^T [B,H,D,T'] (uint2).
// EPI 1: +bias, relu, bf16. EPI 2: +bias(kz==0), fp32 partial slab kz.
template <int EPI, int SPLITK>
__global__ __launch_bounds__(512, 4) void gemm8_kernel(
    const u16* __restrict__ A, const u16* __restrict__ Bt,
    const float* __restrict__ bias,
    u16* __restrict__ out_u, float* __restrict__ out_f,
    u16* __restrict__ qp, u16* __restrict__ kp, u16* __restrict__ vp,
    int Mdim, int Ndim, int Kdim, int gx, int gy) {
  __shared__ u16 la[3][256 * 32];   // 16KB per slot
  __shared__ u16 lb[3][128 * 32];   // 8KB per slot
  const int tid = threadIdx.x, lane = tid & 63, wid = tid >> 6;
  const int wm = wid >> 1, wn = wid & 1;   // wm 0..3, wn 0..1
  const int l15 = lane & 15, l4 = lane >> 4;

  const int nwg = gx * gy * SPLITK;
  const int cpx = nwg >> 3;
  const int wg = (blockIdx.x & 7) * cpx + (blockIdx.x >> 3);
  const int bx = wg % gx;
  const int byz = wg / gx;
  const int by = byz % gy;
  const int kz = byz / gy;
  const int m0 = by * 256, n0 = bx * 128;
  const int Ks = Kdim / SPLITK;
  const int kbase = kz * Ks;
  const int niter = Ks / 32;

  auto stage = [&](int it, int slot) {
    const int k0 = kbase + it * 32;
#pragma unroll
    for (int j = 0; j < 2; ++j) {   // A: 1024 chunks, 2/thread
      const int ci = j * 512 + tid;
      const int row = ci >> 2, sl = ci & 3;
      const int ke = (sl ^ ((row >> 1) & 3)) * 8;
      GLOAD_LDS16(A + (size_t)(m0 + row) * Kdim + k0 + ke, la[slot] + (size_t)ci * 8);
    }
    {                               // B: 512 chunks, 1/thread
      const int ci = tid;
      const int row = ci >> 2, sl = ci & 3;
      const int ke = (sl ^ ((row >> 1) & 3)) * 8;
      GLOAD_LDS16(Bt + (size_t)(n0 + row) * Kdim + k0 + ke, lb[slot] + (size_t)ci * 8);
    }
  };

  f32x4 acc[4][4] = {};
  stage(0, 0);
  stage(1, 1);                       // 6 loads in flight
  asm volatile("s_waitcnt vmcnt(3)" ::: "memory");  // tile0 landed
  __builtin_amdgcn_s_barrier();

  for (int it = 0; it < niter; ++it) {
    const int slot = it % 3;
    if (it + 2 < niter) stage(it + 2, (it + 2) % 3);
    const char* lac = (const char*)la[slot];
    const char* lbc = (const char*)lb[slot];
    bf16x8 af[4], bfr[4];
#pragma unroll
    for (int i = 0; i < 4; ++i) {
      const int ra = wm * 64 + i * 16 + l15;
      af[i]  = *(const bf16x8*)(lac + ra * 64 + ((l4 * 16) ^ (((ra >> 1) & 3) << 4)));
      const int rb = wn * 64 + i * 16 + l15;
      bfr[i] = *(const bf16x8*)(lbc + rb * 64 + ((l4 * 16) ^ (((rb >> 1) & 3) << 4)));
    }
    __builtin_amdgcn_s_setprio(1);
#pragma unroll
    for (int mi = 0; mi < 4; ++mi)
#pragma unroll
      for (int ni = 0; ni < 4; ++ni)
        acc[mi][ni] = mfma16(af[mi], bfr[ni], acc[mi][ni]);
    __builtin_amdgcn_s_setprio(0);
    if (it + 2 < niter)
      asm volatile("s_waitcnt vmcnt(3)" ::: "memory");  // tile it+1 landed (counted)
    else
      asm volatile("s_waitcnt vmcnt(0)" ::: "memory");  // epilogue drain
    __builtin_amdgcn_s_barrier();
  }

#pragma unroll
  for (int mi = 0; mi < 4; ++mi)
#pragma unroll
    for (int ni = 0; ni < 4; ++ni) {
      const int mb = m0 + wm * 64 + mi * 16 + l4 * 4;   // base t, mb&3 == 0
      const int n = n0 + wn * 64 + ni * 16 + l15;
      if constexpr (EPI == 0) {
        const int b = mb >> 11, tb = mb & 2047;
        const int which = n / (Hh * Dd);
        const int nn = n - which * (Hh * Dd);
        const int h = nn >> 6, d = nn & 63;
        if (which == 2) {
          uint2 pw;
          pw.x = cvt_pk_bf16(acc[mi][ni][0], acc[mi][ni][1]);
          pw.y = cvt_pk_bf16(acc[mi][ni][2], acc[mi][ni][3]);
          const int tp = (tb & ~15) | ((tb & 4) << 1) | ((tb & 8) >> 1);
          *(uint2*)(vp + ((size_t)(b * Hh + h) * Dd + d) * Tt + tp) = pw;
        } else {
          u16* dst = (which == 0) ? qp : kp;
#pragma unroll
          for (int r = 0; r < 4; ++r)
            dst[((size_t)(b * Hh + h) * Tt + tb + r) * Dd + d] = f2bf(acc[mi][ni][r]);
        }
      } else if constexpr (EPI == 1) {
#pragma unroll
        for (int r = 0; r < 4; ++r) {
          float val = acc[mi][ni][r] + bias[n];
          val = fmaxf(val, 0.0f);
          out_u[(size_t)(mb + r) * Ndim + n] = f2bf(val);
        }
      } else {
#pragma unroll
        for (int r = 0; r < 4; ++r) {
          float val = acc[mi][ni][r];
          if (kz == 0) val += bias[n];
          out_f[(size_t)kz * Mdim * Ndim + (size_t)(mb + r) * Ndim + n] = val;
        }
      }
    }
}

// ---------------- flash attention: 32x32 MFMA, in-register P, paired q-tiles ------
// Partials now written in bf16 (halves slab traffic; error << headroom).
__global__ __launch_bounds__(256) void attn_kernel(const u16* __restrict__ q,
                                                   const u16* __restrict__ k,
                                                   const u16* __restrict__ vtg,
                                                   u16* __restrict__ Pb,
                                                   float* __restrict__ Lb) {
  __shared__ u16 kl[2][64 * 64];     // K tile [s][d], swizzled 128B rows
  __shared__ u16 vt[2][64 * 64];     // V^T tile [d][s'] sigma-permuted, swizzled
  const int tid = threadIdx.x, lane = tid & 63, w = tid >> 6;   // w 0..3
  const int l31 = lane & 31, hi = lane >> 5;
  const int bid = blockIdx.x;
  const int x8 = bid & 7, r3 = bid >> 3;
  const int g = r3 % 3, u = r3 / 3;          // u 0..39
  int q128, c, nt;
  if (u < 4)       { q128 = 15; c = u; nt = 8; }
  else if (u < 16) { const int v = u - 4;  q128 = 14 - v / 3; c = v % 3; nt = 8; }
  else if (u < 24) { const int v = u - 16; q128 = 10 - v / 2; c = v % 2; nt = 8; }
  else if (u < 28) { q128 = 6 - (u - 24); c = 0; nt = 8; }
  else             { const int v = u - 28; const int row = v >> 2, col = v & 3;
                     nt = 6 - 2 * row; q128 = 14 - row - 4 * col; c = 3 - col; }
  const int ts0 = c * 8;
  const int bh = g * 8 + x8;
  const int wq = 2 * q128 + (w >> 1);
  const int tg = q128 * 128 + (w >> 1) * 64 + (w & 1) * 32 + l31;
  constexpr float SC = 0.18033688f;          // log2(e)/8

  const u16* kgb = k + (size_t)bh * Tt * Dd;
  const u16* vgb = vtg + (size_t)bh * Dd * Tt;

  bf16x8 qf[4];
#pragma unroll
  for (int kt = 0; kt < 4; ++kt)
    qf[kt] = *(const bf16x8*)(q + ((size_t)bh * Tt + tg) * Dd + kt * 16 + hi * 8);

  {
    const int sb0 = ts0 * 64;
#pragma unroll
    for (int jj = 0; jj < 2; ++jj) {
      const int cb = (w * 2 + jj) * 64;
      const int ci = cb + lane;
      const int row = ci >> 3;
      const int sb = ((ci & 7) * 16) ^ ((row & 7) << 4);
      GLOAD_LDS16(kgb + (size_t)(sb0 + row) * Dd + (sb >> 1), kl[0] + (size_t)cb * 8);
      GLOAD_LDS16(vgb + (size_t)row * Tt + sb0 + (sb >> 1), vt[0] + (size_t)cb * 8);
    }
  }

  f32x16 oacc0 = {}, oacc1 = {};
  float lrun = 0.f;

  for (int jt = 0; jt < nt; ++jt) {
    __syncthreads();
    const int cur = jt & 1;
    if (jt + 1 < nt) {
      const int s0n = (ts0 + jt + 1) * 64;
#pragma unroll
      for (int jj = 0; jj < 2; ++jj) {
        const int cb = (w * 2 + jj) * 64;
        const int ci = cb + lane;
        const int row = ci >> 3;
        const int sb = ((ci & 7) * 16) ^ ((row & 7) << 4);
        GLOAD_LDS16(kgb + (size_t)(s0n + row) * Dd + (sb >> 1), kl[cur ^ 1] + (size_t)cb * 8);
        GLOAD_LDS16(vgb + (size_t)row * Tt + s0n + (sb >> 1), vt[cur ^ 1] + (size_t)cb * 8);
      }
    }
    const int tile = ts0 + jt;
    if (tile <= wq) {
      const u16* klc = kl[cur];
      const u16* vtc = vt[cur];

      f32x16 sacc0 = {}, sacc1 = {};
      __builtin_amdgcn_s_setprio(1);
#pragma unroll
      for (int kt = 0; kt < 4; ++kt) {
        const int b0 = kt * 32 + hi * 16;
        const bf16x8 kf0 = *(const bf16x8*)((const char*)klc + KSWZ(l31, b0));
        const bf16x8 kf1 = *(const bf16x8*)((const char*)klc + KSWZ(32 + l31, b0));
        sacc0 = mfma32(kf0, qf[kt], sacc0);
        sacc1 = mfma32(kf1, qf[kt], sacc1);
      }
      __builtin_amdgcn_s_setprio(0);

      const bool diag = (tile == wq);
      bf16x8 pf[4];
      float rs = 0.f;
#pragma unroll
      for (int sh = 0; sh < 2; ++sh) {
        const f32x16 sa = sh ? sacc1 : sacc0;
#pragma unroll
        for (int kt2 = 0; kt2 < 2; ++kt2) {
          float p8[8];
#pragma unroll
          for (int o = 0; o < 8; ++o) {
            const int r = kt2 * 8 + o;
            float e = __builtin_amdgcn_exp2f(sa[r] * SC);
            if (diag) {
              const int sg = tile * 64 + sh * 32 + kt2 * 16 + (o & 3) + 8 * (o >> 2) + 4 * hi;
              e = (sg > tg) ? 0.f : e;
            }
            p8[o] = e;
            rs += e;
          }
          uint4 uu;
          uu.x = cvt_pk_bf16(p8[0], p8[1]);
          uu.y = cvt_pk_bf16(p8[2], p8[3]);
          uu.z = cvt_pk_bf16(p8[4], p8[5]);
          uu.w = cvt_pk_bf16(p8[6], p8[7]);
          pf[sh * 2 + kt2] = __builtin_bit_cast(bf16x8, uu);
        }
      }
      lrun += rs;

      __builtin_amdgcn_s_setprio(1);
#pragma unroll
      for (int ks = 0; ks < 4; ++ks) {
        const int b0 = ks * 32 + hi * 16;
        const bf16x8 vf0 = *(const bf16x8*)((const char*)vtc + KSWZ(l31, b0));
        const bf16x8 vf1 = *(const bf16x8*)((const char*)vtc + KSWZ(32 + l31, b0));
        oacc0 = mfma32(vf0, pf[ks], oacc0);
        oacc1 = mfma32(vf1, pf[ks], oacc1);
      }
      __builtin_amdgcn_s_setprio(0);
    }
  }

  const float lt = lrun + __shfl_xor(lrun, 32);
  const int b = bh / Hh, h = bh - (bh / Hh) * Hh;
  u16* orow = Pb + (size_t)c * MROWS * Ee + ((size_t)b * Tt + tg) * Ee + h * Dd;
#pragma unroll
  for (int dt = 0; dt < 2; ++dt) {
    const f32x16 oa = dt ? oacc1 : oacc0;
#pragma unroll
    for (int kq = 0; kq < 4; ++kq) {
      uint2 pw;
      pw.x = cvt_pk_bf16(oa[4 * kq + 0], oa[4 * kq + 1]);
      pw.y = cvt_pk_bf16(oa[4 * kq + 2], oa[4 * kq + 3]);
      *(uint2*)(orow + dt * 32 + 8 * kq + 4 * hi) = pw;
    }
  }
  if (hi == 0)
    Lb[(size_t)c * MROWS * 12 + ((size_t)b * Tt + tg) * 12 + h] = lt;
}

// ---------------- LN1: combine bf16 attention partials + residual + layernorm -----
__global__ __launch_bounds__(256) void ln1_kernel(const float* __restrict__ x,
                                                  const u16* __restrict__ P,
                                                  const float* __restrict__ L,
                                                  const float* __restrict__ g,
                                                  const float* __restrict__ beta,
                                                  float* __restrict__ yout,
                                                  u16* __restrict__ ybout) {
  const int m = blockIdx.x;
  const int t = m & (Tt - 1);
  __shared__ float ls[12];
  __shared__ float rs[8], rss[8];
  if (threadIdx.x < 12) {
    float s = L[(size_t)m * 12 + threadIdx.x];
    if (t >= 512)  s += L[(size_t)1 * MROWS * 12 + (size_t)m * 12 + threadIdx.x];
    if (t >= 1024) s += L[(size_t)2 * MROWS * 12 + (size_t)m * 12 + threadIdx.x];
    if (t >= 1536) s += L[(size_t)3 * MROWS * 12 + (size_t)m * 12 + threadIdx.x];
    ls[threadIdx.x] = 1.0f / s;
  }
  __syncthreads();
  float vbuf[3];
  float s = 0.f, ss = 0.f;
#pragma unroll
  for (int i = 0; i < 3; ++i) {
    const int e = threadIdx.x + i * 256;
    float o = bf2f(P[(size_t)m * Ee + e]);
    if (t >= 512)  o += bf2f(P[(size_t)1 * MROWS * Ee + (size_t)m * Ee + e]);
    if (t >= 1024) o += bf2f(P[(size_t)2 * MROWS * Ee + (size_t)m * Ee + e]);
    if (t >= 1536) o += bf2f(P[(size_t)3 * MROWS * Ee + (size_t)m * Ee + e]);
    const float tv = x[(size_t)m * Ee + e] + o * ls[e >> 6];
    vbuf[i] = tv;
    s += tv;
    ss += tv * tv;
  }
#pragma unroll
  for (int off = 32; off; off >>= 1) {
    s += __shfl_xor(s, off);
    ss += __shfl_xor(ss, off);
  }
  const int wv = threadIdx.x >> 6, ln = threadIdx.x & 63;
  if (ln == 0) { rs[wv] = s; rss[wv] = ss; }
  __syncthreads();
  if (threadIdx.x == 0) {
    float S = 0.f, SS = 0.f;
    for (int i = 0; i < 4; ++i) { S += rs[i]; SS += rss[i]; }
    rs[4] = S; rss[4] = SS;
  }
  __syncthreads();
  const float mu = rs[4] / Ee;
  const float var = rss[4] / Ee - mu * mu;
  const float inv = rsqrtf(var + 1e-5f);
#pragma unroll
  for (int i = 0; i < 3; ++i) {
    const int e = threadIdx.x + i * 256;
    const float tv = (vbuf[i] - mu) * inv * g[e] + beta[e];
    yout[(size_t)m * Ee + e] = tv;
    ybout[(size_t)m * Ee + e] = f2bf(tv);
  }
}

// ---------------- LN2: residual + 2 split-K partials + layernorm ----------------
__global__ __launch_bounds__(256) void ln2_kernel(const float* __restrict__ a,
                                                  const float* __restrict__ mlp,
                                                  const float* __restrict__ g,
                                                  const float* __restrict__ beta,
                                                  float* __restrict__ yout) {
  const int m = blockIdx.x;
  float vbuf[3];
  float s = 0.f, ss = 0.f;
#pragma unroll
  for (int i = 0; i < 3; ++i) {
    const int e = threadIdx.x + i * 256;
    float t = a[(size_t)m * Ee + e];
#pragma unroll
    for (int kz = 0; kz < 2; ++kz)
      t += mlp[(size_t)kz * MROWS * Ee + (size_t)m * Ee + e];
    vbuf[i] = t;
    s += t;
    ss += t * t;
  }
#pragma unroll
  for (int off = 32; off; off >>= 1) {
    s += __shfl_xor(s, off);
    ss += __shfl_xor(ss, off);
  }
  __shared__ float rs[8], rss[8];
  const int wv = threadIdx.x >> 6, ln = threadIdx.x & 63;
  if (ln == 0) { rs[wv] = s; rss[wv] = ss; }
  __syncthreads();
  if (threadIdx.x == 0) {
    float S = 0.f, SS = 0.f;
    for (int i = 0; i < 4; ++i) { S += rs[i]; SS += rss[i]; }
    rs[4] = S; rss[4] = SS;
  }
  __syncthreads();
  const float mu = rs[4] / Ee;
  const float var = rss[4] / Ee - mu * mu;
  const float inv = rsqrtf(var + 1e-5f);
#pragma unroll
  for (int i = 0; i < 3; ++i) {
    const int e = threadIdx.x + i * 256;
    yout[(size_t)m * Ee + e] = (vbuf[i] - mu) * inv * g[e] + beta[e];
  }
}

// ---------------- launch ----------------
extern "C" void kernel_launch(void* const* d_in, const int* in_sizes, int n_in,
                              void* d_out, int out_size, void* d_ws, size_t ws_size,
                              hipStream_t stream) {
  const float* x  = (const float*)d_in[0];
  const float* Wq = (const float*)d_in[1];
  const float* Wk = (const float*)d_in[2];
  const float* Wv = (const float*)d_in[3];
  const float* W1 = (const float*)d_in[4];
  const float* b1 = (const float*)d_in[5];
  const float* W2 = (const float*)d_in[6];
  const float* b2 = (const float*)d_in[7];
  const float* g1 = (const float*)d_in[8];
  const float* be1 = (const float*)d_in[9];
  const float* g2 = (const float*)d_in[10];
  const float* be2 = (const float*)d_in[11];
  float* out = (float*)d_out;

  char* ws = (char*)d_ws;
  size_t off = 0;
  auto alloc = [&](size_t bytes) -> char* {
    char* p = ws + off;
    off += (bytes + 255) & ~(size_t)255;
    return p;
  };
  u16* xb    = (u16*)alloc((size_t)MROWS * Ee * 2);
  u16* wqkvt = (u16*)alloc((size_t)NQKV * Ee * 2);
  u16* w1t   = (u16*)alloc((size_t)HIDc * Ee * 2);
  u16* w2t   = (u16*)alloc((size_t)Ee * HIDc * 2);
  u16* qb    = (u16*)alloc((size_t)Bb * Hh * Tt * Dd * 2);
  u16* kb    = (u16*)alloc((size_t)Bb * Hh * Tt * Dd * 2);
  u16* vtb   = (u16*)alloc((size_t)Bb * Hh * Tt * Dd * 2);   // [B,H,D,T'] sigma
  float* y    = (float*)alloc((size_t)MROWS * Ee * 4);
  u16* yb     = (u16*)alloc((size_t)MROWS * Ee * 2);
  float* Lb   = (float*)alloc((size_t)4 * MROWS * 12 * 4);
  // union slab: Pb bf16 (25.2MB, dead after ln1) | hbuf (25.2MB) + mlp 2x12.6MB
  char* big = alloc((size_t)MROWS * HIDc * 2 + (size_t)2 * MROWS * Ee * 4);
  u16* Pb    = (u16*)big;
  u16* hbuf  = (u16*)big;
  float* mlp = (float*)(big + (size_t)MROWS * HIDc * 2);
  (void)ws_size;

  // 1. fused prep (cvt_x + all weight transposes)
  prep_kernel<<<9408, 256, 0, stream>>>(x, xb, Wq, Wk, Wv, wqkvt, W1, w1t, W2, w2t);

  // 2. QKV projection (V written directly as sigma-V^T)
  gemm8_kernel<0, 1><<<18 * 16, 512, 0, stream>>>(
      xb, wqkvt, nullptr, nullptr, nullptr, qb, kb, vtb, MROWS, NQKV, Ee, 18, 16);

  // 3. attention (paired q-tiles, chunked s, bf16 partial O + f32 l)
  attn_kernel<<<960, 256, 0, stream>>>(qb, kb, vtb, Pb, Lb);

  // 4. LN1 (combine partials + residual + LN)
  ln1_kernel<<<MROWS, 256, 0, stream>>>(x, Pb, Lb, g1, be1, y, yb);

  // 5. MLP
  gemm8_kernel<1, 1><<<24 * 16, 512, 0, stream>>>(
      yb, w1t, b1, hbuf, nullptr, nullptr, nullptr, nullptr, MROWS, HIDc, Ee, 24, 16);
  gemm8_kernel<2, 2><<<6 * 16 * 2, 512, 0, stream>>>(
      hbuf, w2t, b2, nullptr, mlp, nullptr, nullptr, nullptr, MROWS, Ee, HIDc, 6, 16);

  // 6. LN2 (y + 2 mlp partials) -> output
  ln2_kernel<<<MROWS, 256, 0, stream>>>(y, mlp, g2, be2, out);
}

// Round 16
// 151.972 us; speedup vs baseline: 1.1588x; 1.1588x over previous
//
#include <hip/hip_runtime.h>
#include <stdint.h>

// Problem constants
constexpr int Ee   = 768;
constexpr int Hh   = 12;
constexpr int Dd   = 64;
constexpr int Tt   = 2048;
constexpr int Bb   = 2;
constexpr int HIDc = 3072;
constexpr int MROWS = Bb * Tt;        // 4096
constexpr int NQKV  = 3 * Hh * Dd;    // 2304

typedef unsigned short u16;
typedef __bf16 bf16;
typedef bf16 bf16x8 __attribute__((ext_vector_type(8)));
typedef float f32x4 __attribute__((ext_vector_type(4)));
typedef float f32x16 __attribute__((ext_vector_type(16)));

__device__ __forceinline__ u16 f2bf(float f) {
  uint32_t u = __builtin_bit_cast(uint32_t, f);
  u += 0x7fffu + ((u >> 16) & 1u);
  return (u16)(u >> 16);
}

__device__ __forceinline__ float bf2f(u16 v) {
  uint32_t u = (uint32_t)v << 16;
  return __builtin_bit_cast(float, u);
}

__device__ __forceinline__ uint32_t cvt_pk_bf16(float lo, float hi) {
  uint32_t r;
  asm("v_cvt_pk_bf16_f32 %0, %1, %2" : "=v"(r) : "v"(lo), "v"(hi));
  return r;
}

__device__ __forceinline__ f32x4 mfma16(bf16x8 a, bf16x8 b, f32x4 c) {
  return __builtin_amdgcn_mfma_f32_16x16x32_bf16(a, b, c, 0, 0, 0);
}

__device__ __forceinline__ f32x16 mfma32(bf16x8 a, bf16x8 b, f32x16 c) {
  return __builtin_amdgcn_mfma_f32_32x32x16_bf16(a, b, c, 0, 0, 0);
}

#define GLOAD_LDS16(gp, lp)                                                            \
  __builtin_amdgcn_global_load_lds((const __attribute__((address_space(1))) void*)(gp),\
                                   (__attribute__((address_space(3))) void*)(lp),      \
                                   16, 0, 0)

// XOR swizzle inside a 128-byte LDS row (T2, m201 pattern)
#define KSWZ(row, byte) ((row) * 128 + ((byte) ^ (((row) & 7) << 4)))

// ---------------- fused prep: cvt_x + tr_qkv + tr_w1 + tr_w2 ----------------

__device__ __forceinline__ void tr_body(const float* __restrict__ ip,
                                        u16* __restrict__ op,
                                        int R, int C, int r0, int c0,
                                        float (*t)[33]) {
  const int tx = threadIdx.x & 31, ty = threadIdx.x >> 5;
#pragma unroll
  for (int i = 0; i < 4; ++i)
    t[ty * 4 + i][tx] = ip[(size_t)(r0 + ty * 4 + i) * C + c0 + tx];
  __syncthreads();
#pragma unroll
  for (int i = 0; i < 4; ++i)
    op[(size_t)(c0 + ty * 4 + i) * R + r0 + tx] = f2bf(t[tx][ty * 4 + i]);
}

__global__ __launch_bounds__(256) void prep_kernel(
    const float* __restrict__ x, u16* __restrict__ xb,
    const float* __restrict__ Wq, const float* __restrict__ Wk,
    const float* __restrict__ Wv, u16* __restrict__ wqkvt,
    const float* __restrict__ W1, u16* __restrict__ w1t,
    const float* __restrict__ W2, u16* __restrict__ w2t) {
  __shared__ float t[32][33];
  int bid = blockIdx.x;
  if (bid < 3072) {                 // cvt_x
    const int i = bid * 256 + threadIdx.x;
    const float4 f = *(const float4*)(x + (size_t)i * 4);
    uint2 o;
    u16* po = (u16*)&o;
    po[0] = f2bf(f.x); po[1] = f2bf(f.y); po[2] = f2bf(f.z); po[3] = f2bf(f.w);
    *(uint2*)(xb + (size_t)i * 4) = o;
    return;
  }
  bid -= 3072;
  if (bid < 1728) {                 // tr_qkv
    const int bx = bid & 1;
    const int rest = bid >> 1;
    const int by = rest % 24, z = rest / 24;
    const int which = z / 12, hs = z - which * 12;
    const float* W = (which == 0) ? Wq : (which == 1) ? Wk : Wv;
    tr_body(W + (size_t)hs * Ee * Dd, wqkvt + ((size_t)which * 768 + hs * 64) * Ee,
            Ee, Dd, by * 32, bx * 32, t);
    return;
  }
  bid -= 1728;
  if (bid < 2304) {                 // W1
    const int bx = bid % 96, by = bid / 96;
    tr_body(W1, w1t, Ee, HIDc, by * 32, bx * 32, t);
    return;
  }
  bid -= 2304;
  {                                 // W2
    const int bx = bid % 24, by = bid / 24;
    tr_body(W2, w2t, HIDc, Ee, by * 32, bx * 32, t);
  }
}

// ---------------- GEMM: C[M,N] = A[M,K](bf16) * Bt[N,K](bf16)^T ----------------
// r14 measured-best config: BN=64, BK=64, double-buffered, __syncthreads-based
// (compiler-scheduled waits), XOR-swizzled 128B LDS rows, inverse-swizzled source.
// EPI 0: q/k scatter [B,H,T,D]; V written directly as sigma-V^T [B,H,D,T'] (uint2).
// EPI 1: +bias, relu, bf16. EPI 2: +bias(kz==0), fp32 partial slab kz.
template <int EPI, int BN, int SPLITK>
__global__ __launch_bounds__(256) void gemm_bt_kernel(
    const u16* __restrict__ A, const u16* __restrict__ Bt,
    const float* __restrict__ bias,
    u16* __restrict__ out_u, float* __restrict__ out_f,
    u16* __restrict__ qp, u16* __restrict__ kp, u16* __restrict__ vp,
    int Mdim, int Ndim, int Kdim, int gx, int gy) {
  constexpr int WN = BN / 64;          // 1
  constexpr int WM = 4 / WN;           // 4
  constexpr int MR = 128 / WM / 16;    // 2
  constexpr int ACH = 16;
  constexpr int BCH = BN / 8;          // 8
  __shared__ u16 la[2][128 * 64];
  __shared__ u16 lb[2][BN * 64];
  const int tid = threadIdx.x, lane = tid & 63, wv = tid >> 6;
  const int wm = wv / WN, wn = wv % WN;
  const int l15 = lane & 15, l4 = lane >> 4;

  const int nwg = gx * gy * SPLITK;
  const int cpx = nwg >> 3;
  const int wg = (blockIdx.x & 7) * cpx + (blockIdx.x >> 3);
  const int bx = wg % gx;
  const int byz = wg / gx;
  const int by = byz % gy;
  const int kz = byz / gy;
  const int m0 = by * 128, n0 = bx * BN;
  const int Ks = Kdim / SPLITK;
  const int kbase = kz * Ks;
  const int niter = Ks / 64;

  auto stage = [&](int it, int buf) {
    const int k0 = kbase + it * 64;
#pragma unroll
    for (int j = 0; j < ACH / 4; ++j) {
      const int cb = (wv * (ACH / 4) + j) * 64;
      const int ci = cb + lane;
      const int row = ci >> 3;
      const int kbl = ((ci & 7) * 16) ^ ((row & 7) << 4);
      GLOAD_LDS16(A + (size_t)(m0 + row) * Kdim + k0 + (kbl >> 1), la[buf] + (size_t)cb * 8);
    }
#pragma unroll
    for (int j = 0; j < BCH / 4; ++j) {
      const int cb = (wv * (BCH / 4) + j) * 64;
      const int ci = cb + lane;
      const int row = ci >> 3;
      const int kbl = ((ci & 7) * 16) ^ ((row & 7) << 4);
      GLOAD_LDS16(Bt + (size_t)(n0 + row) * Kdim + k0 + (kbl >> 1), lb[buf] + (size_t)cb * 8);
    }
  };

  f32x4 acc[MR][4] = {};
  stage(0, 0);

  for (int it = 0; it < niter; ++it) {
    __syncthreads();                 // tile it landed; buf[it^1] readers done
    const int cur = it & 1;
    if (it + 1 < niter) stage(it + 1, cur ^ 1);
    const char* lac = (const char*)la[cur];
    const char* lbc = (const char*)lb[cur];
#pragma unroll
    for (int ks = 0; ks < 2; ++ks) {
      bf16x8 af[MR], bfr[4];
#pragma unroll
      for (int i = 0; i < MR; ++i) {
        const int row = wm * (MR * 16) + i * 16 + l15;
        af[i] = *(const bf16x8*)(lac + row * 128 +
                                 (((ks * 64 + l4 * 16)) ^ ((row & 7) << 4)));
      }
#pragma unroll
      for (int i = 0; i < 4; ++i) {
        const int row = wn * 64 + i * 16 + l15;
        bfr[i] = *(const bf16x8*)(lbc + row * 128 +
                                  (((ks * 64 + l4 * 16)) ^ ((row & 7) << 4)));
      }
      __builtin_amdgcn_s_setprio(1);
#pragma unroll
      for (int mi = 0; mi < MR; ++mi)
#pragma unroll
        for (int ni = 0; ni < 4; ++ni)
          acc[mi][ni] = mfma16(af[mi], bfr[ni], acc[mi][ni]);
      __builtin_amdgcn_s_setprio(0);
    }
  }

#pragma unroll
  for (int mi = 0; mi < MR; ++mi)
#pragma unroll
    for (int ni = 0; ni < 4; ++ni) {
      const int mb = m0 + wm * (MR * 16) + mi * 16 + l4 * 4;   // base t, mb&3 == 0
      const int n = n0 + wn * 64 + ni * 16 + l15;
      if constexpr (EPI == 0) {
        const int b = mb >> 11, tb = mb & 2047;
        const int which = n / (Hh * Dd);
        const int nn = n - which * (Hh * Dd);
        const int h = nn >> 6, d = nn & 63;
        if (which == 2) {
          // sigma-V^T direct: t' = swap bits 2<->3 of tb (tb&3==0), 4-run contiguous
          uint2 pw;
          pw.x = cvt_pk_bf16(acc[mi][ni][0], acc[mi][ni][1]);
          pw.y = cvt_pk_bf16(acc[mi][ni][2], acc[mi][ni][3]);
          const int tp = (tb & ~15) | ((tb & 4) << 1) | ((tb & 8) >> 1);
          *(uint2*)(vp + ((size_t)(b * Hh + h) * Dd + d) * Tt + tp) = pw;
        } else {
          u16* dst = (which == 0) ? qp : kp;
#pragma unroll
          for (int r = 0; r < 4; ++r)
            dst[((size_t)(b * Hh + h) * Tt + tb + r) * Dd + d] = f2bf(acc[mi][ni][r]);
        }
      } else if constexpr (EPI == 1) {
#pragma unroll
        for (int r = 0; r < 4; ++r) {
          float val = acc[mi][ni][r] + bias[n];
          val = fmaxf(val, 0.0f);
          out_u[(size_t)(mb + r) * Ndim + n] = f2bf(val);
        }
      } else {
#pragma unroll
        for (int r = 0; r < 4; ++r) {
          float val = acc[mi][ni][r];
          if (kz == 0) val += bias[n];
          out_f[(size_t)kz * Mdim * Ndim + (size_t)(mb + r) * Ndim + n] = val;
        }
      }
    }
}

// ---------------- flash attention: 32x32 MFMA, in-register P, paired q-tiles ------
// Partials written in bf16 (halves slab traffic; verified absmax unchanged).
__global__ __launch_bounds__(256) void attn_kernel(const u16* __restrict__ q,
                                                   const u16* __restrict__ k,
                                                   const u16* __restrict__ vtg,
                                                   u16* __restrict__ Pb,
                                                   float* __restrict__ Lb) {
  __shared__ u16 kl[2][64 * 64];     // K tile [s][d], swizzled 128B rows
  __shared__ u16 vt[2][64 * 64];     // V^T tile [d][s'] sigma-permuted, swizzled
  const int tid = threadIdx.x, lane = tid & 63, w = tid >> 6;   // w 0..3
  const int l31 = lane & 31, hi = lane >> 5;
  const int bid = blockIdx.x;
  const int x8 = bid & 7, r3 = bid >> 3;
  const int g = r3 % 3, u = r3 / 3;          // u 0..39
  int q128, c, nt;
  if (u < 4)       { q128 = 15; c = u; nt = 8; }
  else if (u < 16) { const int v = u - 4;  q128 = 14 - v / 3; c = v % 3; nt = 8; }
  else if (u < 24) { const int v = u - 16; q128 = 10 - v / 2; c = v % 2; nt = 8; }
  else if (u < 28) { q128 = 6 - (u - 24); c = 0; nt = 8; }
  else             { const int v = u - 28; const int row = v >> 2, col = v & 3;
                     nt = 6 - 2 * row; q128 = 14 - row - 4 * col; c = 3 - col; }
  const int ts0 = c * 8;
  const int bh = g * 8 + x8;
  const int wq = 2 * q128 + (w >> 1);
  const int tg = q128 * 128 + (w >> 1) * 64 + (w & 1) * 32 + l31;
  constexpr float SC = 0.18033688f;          // log2(e)/8

  const u16* kgb = k + (size_t)bh * Tt * Dd;
  const u16* vgb = vtg + (size_t)bh * Dd * Tt;

  bf16x8 qf[4];
#pragma unroll
  for (int kt = 0; kt < 4; ++kt)
    qf[kt] = *(const bf16x8*)(q + ((size_t)bh * Tt + tg) * Dd + kt * 16 + hi * 8);

  {
    const int sb0 = ts0 * 64;
#pragma unroll
    for (int jj = 0; jj < 2; ++jj) {
      const int cb = (w * 2 + jj) * 64;
      const int ci = cb + lane;
      const int row = ci >> 3;
      const int sb = ((ci & 7) * 16) ^ ((row & 7) << 4);
      GLOAD_LDS16(kgb + (size_t)(sb0 + row) * Dd + (sb >> 1), kl[0] + (size_t)cb * 8);
      GLOAD_LDS16(vgb + (size_t)row * Tt + sb0 + (sb >> 1), vt[0] + (size_t)cb * 8);
    }
  }

  f32x16 oacc0 = {}, oacc1 = {};
  float lrun = 0.f;

  for (int jt = 0; jt < nt; ++jt) {
    __syncthreads();
    const int cur = jt & 1;
    if (jt + 1 < nt) {
      const int s0n = (ts0 + jt + 1) * 64;
#pragma unroll
      for (int jj = 0; jj < 2; ++jj) {
        const int cb = (w * 2 + jj) * 64;
        const int ci = cb + lane;
        const int row = ci >> 3;
        const int sb = ((ci & 7) * 16) ^ ((row & 7) << 4);
        GLOAD_LDS16(kgb + (size_t)(s0n + row) * Dd + (sb >> 1), kl[cur ^ 1] + (size_t)cb * 8);
        GLOAD_LDS16(vgb + (size_t)row * Tt + s0n + (sb >> 1), vt[cur ^ 1] + (size_t)cb * 8);
      }
    }
    const int tile = ts0 + jt;
    if (tile <= wq) {
      const u16* klc = kl[cur];
      const u16* vtc = vt[cur];

      f32x16 sacc0 = {}, sacc1 = {};
      __builtin_amdgcn_s_setprio(1);
#pragma unroll
      for (int kt = 0; kt < 4; ++kt) {
        const int b0 = kt * 32 + hi * 16;
        const bf16x8 kf0 = *(const bf16x8*)((const char*)klc + KSWZ(l31, b0));
        const bf16x8 kf1 = *(const bf16x8*)((const char*)klc + KSWZ(32 + l31, b0));
        sacc0 = mfma32(kf0, qf[kt], sacc0);
        sacc1 = mfma32(kf1, qf[kt], sacc1);
      }
      __builtin_amdgcn_s_setprio(0);

      const bool diag = (tile == wq);
      bf16x8 pf[4];
      float rs = 0.f;
#pragma unroll
      for (int sh = 0; sh < 2; ++sh) {
        const f32x16 sa = sh ? sacc1 : sacc0;
#pragma unroll
        for (int kt2 = 0; kt2 < 2; ++kt2) {
          float p8[8];
#pragma unroll
          for (int o = 0; o < 8; ++o) {
            const int r = kt2 * 8 + o;
            float e = __builtin_amdgcn_exp2f(sa[r] * SC);
            if (diag) {
              const int sg = tile * 64 + sh * 32 + kt2 * 16 + (o & 3) + 8 * (o >> 2) + 4 * hi;
              e = (sg > tg) ? 0.f : e;
            }
            p8[o] = e;
            rs += e;
          }
          uint4 uu;
          uu.x = cvt_pk_bf16(p8[0], p8[1]);
          uu.y = cvt_pk_bf16(p8[2], p8[3]);
          uu.z = cvt_pk_bf16(p8[4], p8[5]);
          uu.w = cvt_pk_bf16(p8[6], p8[7]);
          pf[sh * 2 + kt2] = __builtin_bit_cast(bf16x8, uu);
        }
      }
      lrun += rs;

      __builtin_amdgcn_s_setprio(1);
#pragma unroll
      for (int ks = 0; ks < 4; ++ks) {
        const int b0 = ks * 32 + hi * 16;
        const bf16x8 vf0 = *(const bf16x8*)((const char*)vtc + KSWZ(l31, b0));
        const bf16x8 vf1 = *(const bf16x8*)((const char*)vtc + KSWZ(32 + l31, b0));
        oacc0 = mfma32(vf0, pf[ks], oacc0);
        oacc1 = mfma32(vf1, pf[ks], oacc1);
      }
      __builtin_amdgcn_s_setprio(0);
    }
  }

  const float lt = lrun + __shfl_xor(lrun, 32);
  const int b = bh / Hh, h = bh - (bh / Hh) * Hh;
  u16* orow = Pb + (size_t)c * MROWS * Ee + ((size_t)b * Tt + tg) * Ee + h * Dd;
#pragma unroll
  for (int dt = 0; dt < 2; ++dt) {
    const f32x16 oa = dt ? oacc1 : oacc0;
#pragma unroll
    for (int kq = 0; kq < 4; ++kq) {
      uint2 pw;
      pw.x = cvt_pk_bf16(oa[4 * kq + 0], oa[4 * kq + 1]);
      pw.y = cvt_pk_bf16(oa[4 * kq + 2], oa[4 * kq + 3]);
      *(uint2*)(orow + dt * 32 + 8 * kq + 4 * hi) = pw;
    }
  }
  if (hi == 0)
    Lb[(size_t)c * MROWS * 12 + ((size_t)b * Tt + tg) * 12 + h] = lt;
}

// ---------------- LN1: combine bf16 attention partials + residual + layernorm -----
__global__ __launch_bounds__(256) void ln1_kernel(const float* __restrict__ x,
                                                  const u16* __restrict__ P,
                                                  const float* __restrict__ L,
                                                  const float* __restrict__ g,
                                                  const float* __restrict__ beta,
                                                  float* __restrict__ yout,
                                                  u16* __restrict__ ybout) {
  const int m = blockIdx.x;
  const int t = m & (Tt - 1);
  __shared__ float ls[12];
  __shared__ float rs[8], rss[8];
  if (threadIdx.x < 12) {
    float s = L[(size_t)m * 12 + threadIdx.x];
    if (t >= 512)  s += L[(size_t)1 * MROWS * 12 + (size_t)m * 12 + threadIdx.x];
    if (t >= 1024) s += L[(size_t)2 * MROWS * 12 + (size_t)m * 12 + threadIdx.x];
    if (t >= 1536) s += L[(size_t)3 * MROWS * 12 + (size_t)m * 12 + threadIdx.x];
    ls[threadIdx.x] = 1.0f / s;
  }
  __syncthreads();
  float vbuf[3];
  float s = 0.f, ss = 0.f;
#pragma unroll
  for (int i = 0; i < 3; ++i) {
    const int e = threadIdx.x + i * 256;
    float o = bf2f(P[(size_t)m * Ee + e]);
    if (t >= 512)  o += bf2f(P[(size_t)1 * MROWS * Ee + (size_t)m * Ee + e]);
    if (t >= 1024) o += bf2f(P[(size_t)2 * MROWS * Ee + (size_t)m * Ee + e]);
    if (t >= 1536) o += bf2f(P[(size_t)3 * MROWS * Ee + (size_t)m * Ee + e]);
    const float tv = x[(size_t)m * Ee + e] + o * ls[e >> 6];
    vbuf[i] = tv;
    s += tv;
    ss += tv * tv;
  }
#pragma unroll
  for (int off = 32; off; off >>= 1) {
    s += __shfl_xor(s, off);
    ss += __shfl_xor(ss, off);
  }
  const int wv = threadIdx.x >> 6, ln = threadIdx.x & 63;
  if (ln == 0) { rs[wv] = s; rss[wv] = ss; }
  __syncthreads();
  if (threadIdx.x == 0) {
    float S = 0.f, SS = 0.f;
    for (int i = 0; i < 4; ++i) { S += rs[i]; SS += rss[i]; }
    rs[4] = S; rss[4] = SS;
  }
  __syncthreads();
  const float mu = rs[4] / Ee;
  const float var = rss[4] / Ee - mu * mu;
  const float inv = rsqrtf(var + 1e-5f);
#pragma unroll
  for (int i = 0; i < 3; ++i) {
    const int e = threadIdx.x + i * 256;
    const float tv = (vbuf[i] - mu) * inv * g[e] + beta[e];
    yout[(size_t)m * Ee + e] = tv;
    ybout[(size_t)m * Ee + e] = f2bf(tv);
  }
}

// ---------------- LN2: residual + 2 split-K partials + layernorm ----------------
__global__ __launch_bounds__(256) void ln2_kernel(const float* __restrict__ a,
                                                  const float* __restrict__ mlp,
                                                  const float* __restrict__ g,
                                                  const float* __restrict__ beta,
                                                  float* __restrict__ yout) {
  const int m = blockIdx.x;
  float vbuf[3];
  float s = 0.f, ss = 0.f;
#pragma unroll
  for (int i = 0; i < 3; ++i) {
    const int e = threadIdx.x + i * 256;
    float t = a[(size_t)m * Ee + e];
#pragma unroll
    for (int kz = 0; kz < 2; ++kz)
      t += mlp[(size_t)kz * MROWS * Ee + (size_t)m * Ee + e];
    vbuf[i] = t;
    s += t;
    ss += t * t;
  }
#pragma unroll
  for (int off = 32; off; off >>= 1) {
    s += __shfl_xor(s, off);
    ss += __shfl_xor(ss, off);
  }
  __shared__ float rs[8], rss[8];
  const int wv = threadIdx.x >> 6, ln = threadIdx.x & 63;
  if (ln == 0) { rs[wv] = s; rss[wv] = ss; }
  __syncthreads();
  if (threadIdx.x == 0) {
    float S = 0.f, SS = 0.f;
    for (int i = 0; i < 4; ++i) { S += rs[i]; SS += rss[i]; }
    rs[4] = S; rss[4] = SS;
  }
  __syncthreads();
  const float mu = rs[4] / Ee;
  const float var = rss[4] / Ee - mu * mu;
  const float inv = rsqrtf(var + 1e-5f);
#pragma unroll
  for (int i = 0; i < 3; ++i) {
    const int e = threadIdx.x + i * 256;
    yout[(size_t)m * Ee + e] = (vbuf[i] - mu) * inv * g[e] + beta[e];
  }
}

// ---------------- launch ----------------
extern "C" void kernel_launch(void* const* d_in, const int* in_sizes, int n_in,
                              void* d_out, int out_size, void* d_ws, size_t ws_size,
                              hipStream_t stream) {
  const float* x  = (const float*)d_in[0];
  const float* Wq = (const float*)d_in[1];
  const float* Wk = (const float*)d_in[2];
  const float* Wv = (const float*)d_in[3];
  const float* W1 = (const float*)d_in[4];
  const float* b1 = (const float*)d_in[5];
  const float* W2 = (const float*)d_in[6];
  const float* b2 = (const float*)d_in[7];
  const float* g1 = (const float*)d_in[8];
  const float* be1 = (const float*)d_in[9];
  const float* g2 = (const float*)d_in[10];
  const float* be2 = (const float*)d_in[11];
  float* out = (float*)d_out;

  char* ws = (char*)d_ws;
  size_t off = 0;
  auto alloc = [&](size_t bytes) -> char* {
    char* p = ws + off;
    off += (bytes + 255) & ~(size_t)255;
    return p;
  };
  u16* xb    = (u16*)alloc((size_t)MROWS * Ee * 2);
  u16* wqkvt = (u16*)alloc((size_t)NQKV * Ee * 2);
  u16* w1t   = (u16*)alloc((size_t)HIDc * Ee * 2);
  u16* w2t   = (u16*)alloc((size_t)Ee * HIDc * 2);
  u16* qb    = (u16*)alloc((size_t)Bb * Hh * Tt * Dd * 2);
  u16* kb    = (u16*)alloc((size_t)Bb * Hh * Tt * Dd * 2);
  u16* vtb   = (u16*)alloc((size_t)Bb * Hh * Tt * Dd * 2);   // [B,H,D,T'] sigma
  float* y    = (float*)alloc((size_t)MROWS * Ee * 4);
  u16* yb     = (u16*)alloc((size_t)MROWS * Ee * 2);
  float* Lb   = (float*)alloc((size_t)4 * MROWS * 12 * 4);
  // union slab: Pb bf16 (25.2MB, dead after ln1) | hbuf (25.2MB) + mlp 2x12.6MB
  char* big = alloc((size_t)MROWS * HIDc * 2 + (size_t)2 * MROWS * Ee * 4);
  u16* Pb    = (u16*)big;
  u16* hbuf  = (u16*)big;
  float* mlp = (float*)(big + (size_t)MROWS * HIDc * 2);
  (void)ws_size;

  // 1. fused prep (cvt_x + all weight transposes)
  prep_kernel<<<9408, 256, 0, stream>>>(x, xb, Wq, Wk, Wv, wqkvt, W1, w1t, W2, w2t);

  // 2. QKV projection (V written directly as sigma-V^T)
  gemm_bt_kernel<0, 64, 1><<<36 * 32, 256, 0, stream>>>(
      xb, wqkvt, nullptr, nullptr, nullptr, qb, kb, vtb, MROWS, NQKV, Ee, 36, 32);

  // 3. attention (paired q-tiles, chunked s, bf16 partial O + f32 l)
  attn_kernel<<<960, 256, 0, stream>>>(qb, kb, vtb, Pb, Lb);

  // 4. LN1 (combine partials + residual + LN)
  ln1_kernel<<<MROWS, 256, 0, stream>>>(x, Pb, Lb, g1, be1, y, yb);

  // 5. MLP
  gemm_bt_kernel<1, 64, 1><<<48 * 32, 256, 0, stream>>>(
      yb, w1t, b1, hbuf, nullptr, nullptr, nullptr, nullptr, MROWS, HIDc, Ee, 48, 32);
  gemm_bt_kernel<2, 64, 2><<<12 * 32 * 2, 256, 0, stream>>>(
      hbuf, w2t, b2, nullptr, mlp, nullptr, nullptr, nullptr, MROWS, Ee, HIDc, 12, 32);

  // 6. LN2 (y + 2 mlp partials) -> output
  ln2_kernel<<<MROWS, 256, 0, stream>>>(y, mlp, g2, be2, out);
}

// Round 17
// 147.945 us; speedup vs baseline: 1.1903x; 1.0272x over previous
//
#include <hip/hip_runtime.h>
#include <stdint.h>

// Problem constants
constexpr int Ee   = 768;
constexpr int Hh   = 12;
constexpr int Dd   = 64;
constexpr int Tt   = 2048;
constexpr int Bb   = 2;
constexpr int HIDc = 3072;
constexpr int MROWS = Bb * Tt;        // 4096
constexpr int NQKV  = 3 * Hh * Dd;    // 2304

typedef unsigned short u16;
typedef __bf16 bf16;
typedef bf16 bf16x8 __attribute__((ext_vector_type(8)));
typedef float f32x4 __attribute__((ext_vector_type(4)));
typedef float f32x16 __attribute__((ext_vector_type(16)));

__device__ __forceinline__ u16 f2bf(float f) {
  uint32_t u = __builtin_bit_cast(uint32_t, f);
  u += 0x7fffu + ((u >> 16) & 1u);
  return (u16)(u >> 16);
}

__device__ __forceinline__ float bf2f(u16 v) {
  uint32_t u = (uint32_t)v << 16;
  return __builtin_bit_cast(float, u);
}

__device__ __forceinline__ uint32_t cvt_pk_bf16(float lo, float hi) {
  uint32_t r;
  asm("v_cvt_pk_bf16_f32 %0, %1, %2" : "=v"(r) : "v"(lo), "v"(hi));
  return r;
}

__device__ __forceinline__ f32x4 mfma16(bf16x8 a, bf16x8 b, f32x4 c) {
  return __builtin_amdgcn_mfma_f32_16x16x32_bf16(a, b, c, 0, 0, 0);
}

__device__ __forceinline__ f32x16 mfma32(bf16x8 a, bf16x8 b, f32x16 c) {
  return __builtin_amdgcn_mfma_f32_32x32x16_bf16(a, b, c, 0, 0, 0);
}

#define GLOAD_LDS16(gp, lp)                                                            \
  __builtin_amdgcn_global_load_lds((const __attribute__((address_space(1))) void*)(gp),\
                                   (__attribute__((address_space(3))) void*)(lp),      \
                                   16, 0, 0)

// XOR swizzle inside a 128-byte LDS row (T2, m201 pattern)
#define KSWZ(row, byte) ((row) * 128 + ((byte) ^ (((row) & 7) << 4)))

// ---------------- fused prep: cvt_x + tr_qkv + tr_w1 + tr_w2 ----------------

__device__ __forceinline__ void tr_body(const float* __restrict__ ip,
                                        u16* __restrict__ op,
                                        int R, int C, int r0, int c0,
                                        float (*t)[33]) {
  const int tx = threadIdx.x & 31, ty = threadIdx.x >> 5;
#pragma unroll
  for (int i = 0; i < 4; ++i)
    t[ty * 4 + i][tx] = ip[(size_t)(r0 + ty * 4 + i) * C + c0 + tx];
  __syncthreads();
#pragma unroll
  for (int i = 0; i < 4; ++i)
    op[(size_t)(c0 + ty * 4 + i) * R + r0 + tx] = f2bf(t[tx][ty * 4 + i]);
}

__global__ __launch_bounds__(256) void prep_kernel(
    const float* __restrict__ x, u16* __restrict__ xb,
    const float* __restrict__ Wq, const float* __restrict__ Wk,
    const float* __restrict__ Wv, u16* __restrict__ wqkvt,
    const float* __restrict__ W1, u16* __restrict__ w1t,
    const float* __restrict__ W2, u16* __restrict__ w2t) {
  __shared__ float t[32][33];
  int bid = blockIdx.x;
  if (bid < 3072) {                 // cvt_x
    const int i = bid * 256 + threadIdx.x;
    const float4 f = *(const float4*)(x + (size_t)i * 4);
    uint2 o;
    u16* po = (u16*)&o;
    po[0] = f2bf(f.x); po[1] = f2bf(f.y); po[2] = f2bf(f.z); po[3] = f2bf(f.w);
    *(uint2*)(xb + (size_t)i * 4) = o;
    return;
  }
  bid -= 3072;
  if (bid < 1728) {                 // tr_qkv
    const int bx = bid & 1;
    const int rest = bid >> 1;
    const int by = rest % 24, z = rest / 24;
    const int which = z / 12, hs = z - which * 12;
    const float* W = (which == 0) ? Wq : (which == 1) ? Wk : Wv;
    tr_body(W + (size_t)hs * Ee * Dd, wqkvt + ((size_t)which * 768 + hs * 64) * Ee,
            Ee, Dd, by * 32, bx * 32, t);
    return;
  }
  bid -= 1728;
  if (bid < 2304) {                 // W1
    const int bx = bid % 96, by = bid / 96;
    tr_body(W1, w1t, Ee, HIDc, by * 32, bx * 32, t);
    return;
  }
  bid -= 2304;
  {                                 // W2
    const int bx = bid % 24, by = bid / 24;
    tr_body(W2, w2t, HIDc, Ee, by * 32, bx * 32, t);
  }
}

// ---------------- GEMM: C[M,N] = A[M,K](bf16) * Bt[N,K](bf16)^T ----------------
// r14 measured-best config: BN=64, BK=64, double-buffered, __syncthreads-based
// (compiler-scheduled waits), XOR-swizzled 128B LDS rows, inverse-swizzled source.
// EPI 0: q/k scatter [B,H,T,D]; V written directly as sigma-V^T [B,H,D,T'] (uint2).
// EPI 1: +bias, relu, bf16. EPI 2: +bias(kz==0), bf16 partial slab kz (uint2).
template <int EPI, int BN, int SPLITK>
__global__ __launch_bounds__(256) void gemm_bt_kernel(
    const u16* __restrict__ A, const u16* __restrict__ Bt,
    const float* __restrict__ bias,
    u16* __restrict__ out_u, u16* __restrict__ out_p,
    u16* __restrict__ qp, u16* __restrict__ kp, u16* __restrict__ vp,
    int Mdim, int Ndim, int Kdim, int gx, int gy) {
  constexpr int WN = BN / 64;          // 1
  constexpr int WM = 4 / WN;           // 4
  constexpr int MR = 128 / WM / 16;    // 2
  constexpr int ACH = 16;
  constexpr int BCH = BN / 8;          // 8
  __shared__ u16 la[2][128 * 64];
  __shared__ u16 lb[2][BN * 64];
  const int tid = threadIdx.x, lane = tid & 63, wv = tid >> 6;
  const int wm = wv / WN, wn = wv % WN;
  const int l15 = lane & 15, l4 = lane >> 4;

  const int nwg = gx * gy * SPLITK;
  const int cpx = nwg >> 3;
  const int wg = (blockIdx.x & 7) * cpx + (blockIdx.x >> 3);
  const int bx = wg % gx;
  const int byz = wg / gx;
  const int by = byz % gy;
  const int kz = byz / gy;
  const int m0 = by * 128, n0 = bx * BN;
  const int Ks = Kdim / SPLITK;
  const int kbase = kz * Ks;
  const int niter = Ks / 64;

  auto stage = [&](int it, int buf) {
    const int k0 = kbase + it * 64;
#pragma unroll
    for (int j = 0; j < ACH / 4; ++j) {
      const int cb = (wv * (ACH / 4) + j) * 64;
      const int ci = cb + lane;
      const int row = ci >> 3;
      const int kbl = ((ci & 7) * 16) ^ ((row & 7) << 4);
      GLOAD_LDS16(A + (size_t)(m0 + row) * Kdim + k0 + (kbl >> 1), la[buf] + (size_t)cb * 8);
    }
#pragma unroll
    for (int j = 0; j < BCH / 4; ++j) {
      const int cb = (wv * (BCH / 4) + j) * 64;
      const int ci = cb + lane;
      const int row = ci >> 3;
      const int kbl = ((ci & 7) * 16) ^ ((row & 7) << 4);
      GLOAD_LDS16(Bt + (size_t)(n0 + row) * Kdim + k0 + (kbl >> 1), lb[buf] + (size_t)cb * 8);
    }
  };

  f32x4 acc[MR][4] = {};
  stage(0, 0);

  for (int it = 0; it < niter; ++it) {
    __syncthreads();                 // tile it landed; buf[it^1] readers done
    const int cur = it & 1;
    if (it + 1 < niter) stage(it + 1, cur ^ 1);
    const char* lac = (const char*)la[cur];
    const char* lbc = (const char*)lb[cur];
#pragma unroll
    for (int ks = 0; ks < 2; ++ks) {
      bf16x8 af[MR], bfr[4];
#pragma unroll
      for (int i = 0; i < MR; ++i) {
        const int row = wm * (MR * 16) + i * 16 + l15;
        af[i] = *(const bf16x8*)(lac + row * 128 +
                                 (((ks * 64 + l4 * 16)) ^ ((row & 7) << 4)));
      }
#pragma unroll
      for (int i = 0; i < 4; ++i) {
        const int row = wn * 64 + i * 16 + l15;
        bfr[i] = *(const bf16x8*)(lbc + row * 128 +
                                  (((ks * 64 + l4 * 16)) ^ ((row & 7) << 4)));
      }
      __builtin_amdgcn_s_setprio(1);
#pragma unroll
      for (int mi = 0; mi < MR; ++mi)
#pragma unroll
        for (int ni = 0; ni < 4; ++ni)
          acc[mi][ni] = mfma16(af[mi], bfr[ni], acc[mi][ni]);
      __builtin_amdgcn_s_setprio(0);
    }
  }

#pragma unroll
  for (int mi = 0; mi < MR; ++mi)
#pragma unroll
    for (int ni = 0; ni < 4; ++ni) {
      const int mb = m0 + wm * (MR * 16) + mi * 16 + l4 * 4;   // base t, mb&3 == 0
      const int n = n0 + wn * 64 + ni * 16 + l15;
      if constexpr (EPI == 0) {
        const int b = mb >> 11, tb = mb & 2047;
        const int which = n / (Hh * Dd);
        const int nn = n - which * (Hh * Dd);
        const int h = nn >> 6, d = nn & 63;
        if (which == 2) {
          // sigma-V^T direct: t' = swap bits 2<->3 of tb (tb&3==0), 4-run contiguous
          uint2 pw;
          pw.x = cvt_pk_bf16(acc[mi][ni][0], acc[mi][ni][1]);
          pw.y = cvt_pk_bf16(acc[mi][ni][2], acc[mi][ni][3]);
          const int tp = (tb & ~15) | ((tb & 4) << 1) | ((tb & 8) >> 1);
          *(uint2*)(vp + ((size_t)(b * Hh + h) * Dd + d) * Tt + tp) = pw;
        } else {
          u16* dst = (which == 0) ? qp : kp;
#pragma unroll
          for (int r = 0; r < 4; ++r)
            dst[((size_t)(b * Hh + h) * Tt + tb + r) * Dd + d] = f2bf(acc[mi][ni][r]);
        }
      } else if constexpr (EPI == 1) {
#pragma unroll
        for (int r = 0; r < 4; ++r) {
          float val = acc[mi][ni][r] + bias[n];
          val = fmaxf(val, 0.0f);
          out_u[(size_t)(mb + r) * Ndim + n] = f2bf(val);
        }
      } else {
#pragma unroll
        for (int r = 0; r < 4; ++r) {
          float val = acc[mi][ni][r];
          if (kz == 0) val += bias[n];
          out_p[(size_t)kz * Mdim * Ndim + (size_t)(mb + r) * Ndim + n] = f2bf(val);
        }
      }
    }
}

// ---------------- flash attention: 32x32 MFMA, in-register P, paired q-tiles ------
__global__ __launch_bounds__(256) void attn_kernel(const u16* __restrict__ q,
                                                   const u16* __restrict__ k,
                                                   const u16* __restrict__ vtg,
                                                   u16* __restrict__ Pb,
                                                   float* __restrict__ Lb) {
  __shared__ u16 kl[2][64 * 64];     // K tile [s][d], swizzled 128B rows
  __shared__ u16 vt[2][64 * 64];     // V^T tile [d][s'] sigma-permuted, swizzled
  const int tid = threadIdx.x, lane = tid & 63, w = tid >> 6;   // w 0..3
  const int l31 = lane & 31, hi = lane >> 5;
  const int bid = blockIdx.x;
  const int x8 = bid & 7, r3 = bid >> 3;
  const int g = r3 % 3, u = r3 / 3;          // u 0..39
  int q128, c, nt;
  if (u < 4)       { q128 = 15; c = u; nt = 8; }
  else if (u < 16) { const int v = u - 4;  q128 = 14 - v / 3; c = v % 3; nt = 8; }
  else if (u < 24) { const int v = u - 16; q128 = 10 - v / 2; c = v % 2; nt = 8; }
  else if (u < 28) { q128 = 6 - (u - 24); c = 0; nt = 8; }
  else             { const int v = u - 28; const int row = v >> 2, col = v & 3;
                     nt = 6 - 2 * row; q128 = 14 - row - 4 * col; c = 3 - col; }
  const int ts0 = c * 8;
  const int bh = g * 8 + x8;
  const int wq = 2 * q128 + (w >> 1);
  const int tg = q128 * 128 + (w >> 1) * 64 + (w & 1) * 32 + l31;
  constexpr float SC = 0.18033688f;          // log2(e)/8

  const u16* kgb = k + (size_t)bh * Tt * Dd;
  const u16* vgb = vtg + (size_t)bh * Dd * Tt;

  bf16x8 qf[4];
#pragma unroll
  for (int kt = 0; kt < 4; ++kt)
    qf[kt] = *(const bf16x8*)(q + ((size_t)bh * Tt + tg) * Dd + kt * 16 + hi * 8);

  {
    const int sb0 = ts0 * 64;
#pragma unroll
    for (int jj = 0; jj < 2; ++jj) {
      const int cb = (w * 2 + jj) * 64;
      const int ci = cb + lane;
      const int row = ci >> 3;
      const int sb = ((ci & 7) * 16) ^ ((row & 7) << 4);
      GLOAD_LDS16(kgb + (size_t)(sb0 + row) * Dd + (sb >> 1), kl[0] + (size_t)cb * 8);
      GLOAD_LDS16(vgb + (size_t)row * Tt + sb0 + (sb >> 1), vt[0] + (size_t)cb * 8);
    }
  }

  f32x16 oacc0 = {}, oacc1 = {};
  float lrun = 0.f;

  for (int jt = 0; jt < nt; ++jt) {
    __syncthreads();
    const int cur = jt & 1;
    if (jt + 1 < nt) {
      const int s0n = (ts0 + jt + 1) * 64;
#pragma unroll
      for (int jj = 0; jj < 2; ++jj) {
        const int cb = (w * 2 + jj) * 64;
        const int ci = cb + lane;
        const int row = ci >> 3;
        const int sb = ((ci & 7) * 16) ^ ((row & 7) << 4);
        GLOAD_LDS16(kgb + (size_t)(s0n + row) * Dd + (sb >> 1), kl[cur ^ 1] + (size_t)cb * 8);
        GLOAD_LDS16(vgb + (size_t)row * Tt + s0n + (sb >> 1), vt[cur ^ 1] + (size_t)cb * 8);
      }
    }
    const int tile = ts0 + jt;
    if (tile <= wq) {
      const u16* klc = kl[cur];
      const u16* vtc = vt[cur];

      f32x16 sacc0 = {}, sacc1 = {};
      __builtin_amdgcn_s_setprio(1);
#pragma unroll
      for (int kt = 0; kt < 4; ++kt) {
        const int b0 = kt * 32 + hi * 16;
        const bf16x8 kf0 = *(const bf16x8*)((const char*)klc + KSWZ(l31, b0));
        const bf16x8 kf1 = *(const bf16x8*)((const char*)klc + KSWZ(32 + l31, b0));
        sacc0 = mfma32(kf0, qf[kt], sacc0);
        sacc1 = mfma32(kf1, qf[kt], sacc1);
      }
      __builtin_amdgcn_s_setprio(0);

      const bool diag = (tile == wq);
      bf16x8 pf[4];
      float rs = 0.f;
#pragma unroll
      for (int sh = 0; sh < 2; ++sh) {
        const f32x16 sa = sh ? sacc1 : sacc0;
#pragma unroll
        for (int kt2 = 0; kt2 < 2; ++kt2) {
          float p8[8];
#pragma unroll
          for (int o = 0; o < 8; ++o) {
            const int r = kt2 * 8 + o;
            float e = __builtin_amdgcn_exp2f(sa[r] * SC);
            if (diag) {
              const int sg = tile * 64 + sh * 32 + kt2 * 16 + (o & 3) + 8 * (o >> 2) + 4 * hi;
              e = (sg > tg) ? 0.f : e;
            }
            p8[o] = e;
            rs += e;
          }
          uint4 uu;
          uu.x = cvt_pk_bf16(p8[0], p8[1]);
          uu.y = cvt_pk_bf16(p8[2], p8[3]);
          uu.z = cvt_pk_bf16(p8[4], p8[5]);
          uu.w = cvt_pk_bf16(p8[6], p8[7]);
          pf[sh * 2 + kt2] = __builtin_bit_cast(bf16x8, uu);
        }
      }
      lrun += rs;

      __builtin_amdgcn_s_setprio(1);
#pragma unroll
      for (int ks = 0; ks < 4; ++ks) {
        const int b0 = ks * 32 + hi * 16;
        const bf16x8 vf0 = *(const bf16x8*)((const char*)vtc + KSWZ(l31, b0));
        const bf16x8 vf1 = *(const bf16x8*)((const char*)vtc + KSWZ(32 + l31, b0));
        oacc0 = mfma32(vf0, pf[ks], oacc0);
        oacc1 = mfma32(vf1, pf[ks], oacc1);
      }
      __builtin_amdgcn_s_setprio(0);
    }
  }

  const float lt = lrun + __shfl_xor(lrun, 32);
  const int b = bh / Hh, h = bh - (bh / Hh) * Hh;
  u16* orow = Pb + (size_t)c * MROWS * Ee + ((size_t)b * Tt + tg) * Ee + h * Dd;
#pragma unroll
  for (int dt = 0; dt < 2; ++dt) {
    const f32x16 oa = dt ? oacc1 : oacc0;
#pragma unroll
    for (int kq = 0; kq < 4; ++kq) {
      uint2 pw;
      pw.x = cvt_pk_bf16(oa[4 * kq + 0], oa[4 * kq + 1]);
      pw.y = cvt_pk_bf16(oa[4 * kq + 2], oa[4 * kq + 3]);
      *(uint2*)(orow + dt * 32 + 8 * kq + 4 * hi) = pw;
    }
  }
  if (hi == 0)
    Lb[(size_t)c * MROWS * 12 + ((size_t)b * Tt + tg) * 12 + h] = lt;
}

// ---------------- LN1: combine bf16 attention partials + residual + layernorm -----
// y written bf16 only (gemm2 input AND ln2 residual).
__global__ __launch_bounds__(256) void ln1_kernel(const float* __restrict__ x,
                                                  const u16* __restrict__ P,
                                                  const float* __restrict__ L,
                                                  const float* __restrict__ g,
                                                  const float* __restrict__ beta,
                                                  u16* __restrict__ ybout) {
  const int m = blockIdx.x;
  const int t = m & (Tt - 1);
  __shared__ float ls[12];
  __shared__ float rs[8], rss[8];
  if (threadIdx.x < 12) {
    float s = L[(size_t)m * 12 + threadIdx.x];
    if (t >= 512)  s += L[(size_t)1 * MROWS * 12 + (size_t)m * 12 + threadIdx.x];
    if (t >= 1024) s += L[(size_t)2 * MROWS * 12 + (size_t)m * 12 + threadIdx.x];
    if (t >= 1536) s += L[(size_t)3 * MROWS * 12 + (size_t)m * 12 + threadIdx.x];
    ls[threadIdx.x] = 1.0f / s;
  }
  __syncthreads();
  float vbuf[3];
  float s = 0.f, ss = 0.f;
#pragma unroll
  for (int i = 0; i < 3; ++i) {
    const int e = threadIdx.x + i * 256;
    float o = bf2f(P[(size_t)m * Ee + e]);
    if (t >= 512)  o += bf2f(P[(size_t)1 * MROWS * Ee + (size_t)m * Ee + e]);
    if (t >= 1024) o += bf2f(P[(size_t)2 * MROWS * Ee + (size_t)m * Ee + e]);
    if (t >= 1536) o += bf2f(P[(size_t)3 * MROWS * Ee + (size_t)m * Ee + e]);
    const float tv = x[(size_t)m * Ee + e] + o * ls[e >> 6];
    vbuf[i] = tv;
    s += tv;
    ss += tv * tv;
  }
#pragma unroll
  for (int off = 32; off; off >>= 1) {
    s += __shfl_xor(s, off);
    ss += __shfl_xor(ss, off);
  }
  const int wv = threadIdx.x >> 6, ln = threadIdx.x & 63;
  if (ln == 0) { rs[wv] = s; rss[wv] = ss; }
  __syncthreads();
  if (threadIdx.x == 0) {
    float S = 0.f, SS = 0.f;
    for (int i = 0; i < 4; ++i) { S += rs[i]; SS += rss[i]; }
    rs[4] = S; rss[4] = SS;
  }
  __syncthreads();
  const float mu = rs[4] / Ee;
  const float var = rss[4] / Ee - mu * mu;
  const float inv = rsqrtf(var + 1e-5f);
#pragma unroll
  for (int i = 0; i < 3; ++i) {
    const int e = threadIdx.x + i * 256;
    const float tv = (vbuf[i] - mu) * inv * g[e] + beta[e];
    ybout[(size_t)m * Ee + e] = f2bf(tv);
  }
}

// ---------------- LN2: bf16 residual + 2 bf16 split-K partials + layernorm --------
__global__ __launch_bounds__(256) void ln2_kernel(const u16* __restrict__ a,
                                                  const u16* __restrict__ mlp,
                                                  const float* __restrict__ g,
                                                  const float* __restrict__ beta,
                                                  float* __restrict__ yout) {
  const int m = blockIdx.x;
  float vbuf[3];
  float s = 0.f, ss = 0.f;
#pragma unroll
  for (int i = 0; i < 3; ++i) {
    const int e = threadIdx.x + i * 256;
    float t = bf2f(a[(size_t)m * Ee + e]);
#pragma unroll
    for (int kz = 0; kz < 2; ++kz)
      t += bf2f(mlp[(size_t)kz * MROWS * Ee + (size_t)m * Ee + e]);
    vbuf[i] = t;
    s += t;
    ss += t * t;
  }
#pragma unroll
  for (int off = 32; off; off >>= 1) {
    s += __shfl_xor(s, off);
    ss += __shfl_xor(ss, off);
  }
  __shared__ float rs[8], rss[8];
  const int wv = threadIdx.x >> 6, ln = threadIdx.x & 63;
  if (ln == 0) { rs[wv] = s; rss[wv] = ss; }
  __syncthreads();
  if (threadIdx.x == 0) {
    float S = 0.f, SS = 0.f;
    for (int i = 0; i < 4; ++i) { S += rs[i]; SS += rss[i]; }
    rs[4] = S; rss[4] = SS;
  }
  __syncthreads();
  const float mu = rs[4] / Ee;
  const float var = rss[4] / Ee - mu * mu;
  const float inv = rsqrtf(var + 1e-5f);
#pragma unroll
  for (int i = 0; i < 3; ++i) {
    const int e = threadIdx.x + i * 256;
    yout[(size_t)m * Ee + e] = (vbuf[i] - mu) * inv * g[e] + beta[e];
  }
}

// ---------------- launch ----------------
extern "C" void kernel_launch(void* const* d_in, const int* in_sizes, int n_in,
                              void* d_out, int out_size, void* d_ws, size_t ws_size,
                              hipStream_t stream) {
  const float* x  = (const float*)d_in[0];
  const float* Wq = (const float*)d_in[1];
  const float* Wk = (const float*)d_in[2];
  const float* Wv = (const float*)d_in[3];
  const float* W1 = (const float*)d_in[4];
  const float* b1 = (const float*)d_in[5];
  const float* W2 = (const float*)d_in[6];
  const float* b2 = (const float*)d_in[7];
  const float* g1 = (const float*)d_in[8];
  const float* be1 = (const float*)d_in[9];
  const float* g2 = (const float*)d_in[10];
  const float* be2 = (const float*)d_in[11];
  float* out = (float*)d_out;

  char* ws = (char*)d_ws;
  size_t off = 0;
  auto alloc = [&](size_t bytes) -> char* {
    char* p = ws + off;
    off += (bytes + 255) & ~(size_t)255;
    return p;
  };
  u16* xb    = (u16*)alloc((size_t)MROWS * Ee * 2);
  u16* wqkvt = (u16*)alloc((size_t)NQKV * Ee * 2);
  u16* w1t   = (u16*)alloc((size_t)HIDc * Ee * 2);
  u16* w2t   = (u16*)alloc((size_t)Ee * HIDc * 2);
  u16* qb    = (u16*)alloc((size_t)Bb * Hh * Tt * Dd * 2);
  u16* kb    = (u16*)alloc((size_t)Bb * Hh * Tt * Dd * 2);
  u16* vtb   = (u16*)alloc((size_t)Bb * Hh * Tt * Dd * 2);   // [B,H,D,T'] sigma
  u16* yb     = (u16*)alloc((size_t)MROWS * Ee * 2);
  float* Lb   = (float*)alloc((size_t)4 * MROWS * 12 * 4);
  // union slab: Pb bf16 (25.2MB, dead after ln1) | hbuf (25.2MB) + mlp 2x6.3MB bf16
  char* big = alloc((size_t)MROWS * HIDc * 2 + (size_t)2 * MROWS * Ee * 2);
  u16* Pb    = (u16*)big;
  u16* hbuf  = (u16*)big;
  u16* mlp   = (u16*)(big + (size_t)MROWS * HIDc * 2);
  (void)ws_size;

  // 1. fused prep (cvt_x + all weight transposes)
  prep_kernel<<<9408, 256, 0, stream>>>(x, xb, Wq, Wk, Wv, wqkvt, W1, w1t, W2, w2t);

  // 2. QKV projection (V written directly as sigma-V^T)
  gemm_bt_kernel<0, 64, 1><<<36 * 32, 256, 0, stream>>>(
      xb, wqkvt, nullptr, nullptr, nullptr, qb, kb, vtb, MROWS, NQKV, Ee, 36, 32);

  // 3. attention (paired q-tiles, chunked s, bf16 partial O + f32 l)
  attn_kernel<<<960, 256, 0, stream>>>(qb, kb, vtb, Pb, Lb);

  // 4. LN1 (combine partials + residual + LN) -> bf16 y only
  ln1_kernel<<<MROWS, 256, 0, stream>>>(x, Pb, Lb, g1, be1, yb);

  // 5. MLP
  gemm_bt_kernel<1, 64, 1><<<48 * 32, 256, 0, stream>>>(
      yb, w1t, b1, hbuf, nullptr, nullptr, nullptr, nullptr, MROWS, HIDc, Ee, 48, 32);
  gemm_bt_kernel<2, 64, 2><<<12 * 32 * 2, 256, 0, stream>>>(
      hbuf, w2t, b2, nullptr, mlp, nullptr, nullptr, nullptr, MROWS, Ee, HIDc, 12, 32);

  // 6. LN2 (yb + 2 bf16 mlp partials) -> output
  ln2_kernel<<<MROWS, 256, 0, stream>>>(yb, mlp, g2, be2, out);
}

// Round 18
// 143.010 us; speedup vs baseline: 1.2314x; 1.0345x over previous
//
#include <hip/hip_runtime.h>
#include <stdint.h>

// Problem constants
constexpr int Ee   = 768;
constexpr int Hh   = 12;
constexpr int Dd   = 64;
constexpr int Tt   = 2048;
constexpr int Bb   = 2;
constexpr int HIDc = 3072;
constexpr int MROWS = Bb * Tt;        // 4096
constexpr int NQKV  = 3 * Hh * Dd;    // 2304

typedef unsigned short u16;
typedef __bf16 bf16;
typedef bf16 bf16x8 __attribute__((ext_vector_type(8)));
typedef float f32x4 __attribute__((ext_vector_type(4)));
typedef float f32x16 __attribute__((ext_vector_type(16)));

__device__ __forceinline__ u16 f2bf(float f) {
  uint32_t u = __builtin_bit_cast(uint32_t, f);
  u += 0x7fffu + ((u >> 16) & 1u);
  return (u16)(u >> 16);
}

__device__ __forceinline__ float bf2f(u16 v) {
  uint32_t u = (uint32_t)v << 16;
  return __builtin_bit_cast(float, u);
}

__device__ __forceinline__ uint32_t cvt_pk_bf16(float lo, float hi) {
  uint32_t r;
  asm("v_cvt_pk_bf16_f32 %0, %1, %2" : "=v"(r) : "v"(lo), "v"(hi));
  return r;
}

__device__ __forceinline__ f32x4 mfma16(bf16x8 a, bf16x8 b, f32x4 c) {
  return __builtin_amdgcn_mfma_f32_16x16x32_bf16(a, b, c, 0, 0, 0);
}

__device__ __forceinline__ f32x16 mfma32(bf16x8 a, bf16x8 b, f32x16 c) {
  return __builtin_amdgcn_mfma_f32_32x32x16_bf16(a, b, c, 0, 0, 0);
}

#define GLOAD_LDS16(gp, lp)                                                            \
  __builtin_amdgcn_global_load_lds((const __attribute__((address_space(1))) void*)(gp),\
                                   (__attribute__((address_space(3))) void*)(lp),      \
                                   16, 0, 0)

// XOR swizzle inside a 128-byte LDS row (T2, m201 pattern)
#define KSWZ(row, byte) ((row) * 128 + ((byte) ^ (((row) & 7) << 4)))

// ---------------- fused prep: cvt_x + tr_qkv + tr_w1 + tr_w2 ----------------

__device__ __forceinline__ void tr_body(const float* __restrict__ ip,
                                        u16* __restrict__ op,
                                        int R, int C, int r0, int c0,
                                        float (*t)[33]) {
  const int tx = threadIdx.x & 31, ty = threadIdx.x >> 5;
#pragma unroll
  for (int i = 0; i < 4; ++i)
    t[ty * 4 + i][tx] = ip[(size_t)(r0 + ty * 4 + i) * C + c0 + tx];
  __syncthreads();
#pragma unroll
  for (int i = 0; i < 4; ++i)
    op[(size_t)(c0 + ty * 4 + i) * R + r0 + tx] = f2bf(t[tx][ty * 4 + i]);
}

__global__ __launch_bounds__(256) void prep_kernel(
    const float* __restrict__ x, u16* __restrict__ xb,
    const float* __restrict__ Wq, const float* __restrict__ Wk,
    const float* __restrict__ Wv, u16* __restrict__ wqkvt,
    const float* __restrict__ W1, u16* __restrict__ w1t,
    const float* __restrict__ W2, u16* __restrict__ w2t) {
  __shared__ float t[32][33];
  int bid = blockIdx.x;
  if (bid < 3072) {                 // cvt_x
    const int i = bid * 256 + threadIdx.x;
    const float4 f = *(const float4*)(x + (size_t)i * 4);
    uint2 o;
    u16* po = (u16*)&o;
    po[0] = f2bf(f.x); po[1] = f2bf(f.y); po[2] = f2bf(f.z); po[3] = f2bf(f.w);
    *(uint2*)(xb + (size_t)i * 4) = o;
    return;
  }
  bid -= 3072;
  if (bid < 1728) {                 // tr_qkv
    const int bx = bid & 1;
    const int rest = bid >> 1;
    const int by = rest % 24, z = rest / 24;
    const int which = z / 12, hs = z - which * 12;
    const float* W = (which == 0) ? Wq : (which == 1) ? Wk : Wv;
    tr_body(W + (size_t)hs * Ee * Dd, wqkvt + ((size_t)which * 768 + hs * 64) * Ee,
            Ee, Dd, by * 32, bx * 32, t);
    return;
  }
  bid -= 1728;
  if (bid < 2304) {                 // W1
    const int bx = bid % 96, by = bid / 96;
    tr_body(W1, w1t, Ee, HIDc, by * 32, bx * 32, t);
    return;
  }
  bid -= 2304;
  {                                 // W2
    const int bx = bid % 24, by = bid / 24;
    tr_body(W2, w2t, HIDc, Ee, by * 32, bx * 32, t);
  }
}

// ---------------- GEMM: C[M,N] = A[M,K](bf16) * Bt[N,K](bf16)^T ----------------
// r14 measured-best config: BN=64, BK=64, double-buffered, __syncthreads-based.
template <int EPI, int BN, int SPLITK>
__global__ __launch_bounds__(256) void gemm_bt_kernel(
    const u16* __restrict__ A, const u16* __restrict__ Bt,
    const float* __restrict__ bias,
    u16* __restrict__ out_u, u16* __restrict__ out_p,
    u16* __restrict__ qp, u16* __restrict__ kp, u16* __restrict__ vp,
    int Mdim, int Ndim, int Kdim, int gx, int gy) {
  constexpr int WN = BN / 64;          // 1
  constexpr int WM = 4 / WN;           // 4
  constexpr int MR = 128 / WM / 16;    // 2
  constexpr int ACH = 16;
  constexpr int BCH = BN / 8;          // 8
  __shared__ u16 la[2][128 * 64];
  __shared__ u16 lb[2][BN * 64];
  const int tid = threadIdx.x, lane = tid & 63, wv = tid >> 6;
  const int wm = wv / WN, wn = wv % WN;
  const int l15 = lane & 15, l4 = lane >> 4;

  const int nwg = gx * gy * SPLITK;
  const int cpx = nwg >> 3;
  const int wg = (blockIdx.x & 7) * cpx + (blockIdx.x >> 3);
  const int bx = wg % gx;
  const int byz = wg / gx;
  const int by = byz % gy;
  const int kz = byz / gy;
  const int m0 = by * 128, n0 = bx * BN;
  const int Ks = Kdim / SPLITK;
  const int kbase = kz * Ks;
  const int niter = Ks / 64;

  auto stage = [&](int it, int buf) {
    const int k0 = kbase + it * 64;
#pragma unroll
    for (int j = 0; j < ACH / 4; ++j) {
      const int cb = (wv * (ACH / 4) + j) * 64;
      const int ci = cb + lane;
      const int row = ci >> 3;
      const int kbl = ((ci & 7) * 16) ^ ((row & 7) << 4);
      GLOAD_LDS16(A + (size_t)(m0 + row) * Kdim + k0 + (kbl >> 1), la[buf] + (size_t)cb * 8);
    }
#pragma unroll
    for (int j = 0; j < BCH / 4; ++j) {
      const int cb = (wv * (BCH / 4) + j) * 64;
      const int ci = cb + lane;
      const int row = ci >> 3;
      const int kbl = ((ci & 7) * 16) ^ ((row & 7) << 4);
      GLOAD_LDS16(Bt + (size_t)(n0 + row) * Kdim + k0 + (kbl >> 1), lb[buf] + (size_t)cb * 8);
    }
  };

  f32x4 acc[MR][4] = {};
  stage(0, 0);

  for (int it = 0; it < niter; ++it) {
    __syncthreads();                 // tile it landed; buf[it^1] readers done
    const int cur = it & 1;
    if (it + 1 < niter) stage(it + 1, cur ^ 1);
    const char* lac = (const char*)la[cur];
    const char* lbc = (const char*)lb[cur];
#pragma unroll
    for (int ks = 0; ks < 2; ++ks) {
      bf16x8 af[MR], bfr[4];
#pragma unroll
      for (int i = 0; i < MR; ++i) {
        const int row = wm * (MR * 16) + i * 16 + l15;
        af[i] = *(const bf16x8*)(lac + row * 128 +
                                 (((ks * 64 + l4 * 16)) ^ ((row & 7) << 4)));
      }
#pragma unroll
      for (int i = 0; i < 4; ++i) {
        const int row = wn * 64 + i * 16 + l15;
        bfr[i] = *(const bf16x8*)(lbc + row * 128 +
                                  (((ks * 64 + l4 * 16)) ^ ((row & 7) << 4)));
      }
      __builtin_amdgcn_s_setprio(1);
#pragma unroll
      for (int mi = 0; mi < MR; ++mi)
#pragma unroll
        for (int ni = 0; ni < 4; ++ni)
          acc[mi][ni] = mfma16(af[mi], bfr[ni], acc[mi][ni]);
      __builtin_amdgcn_s_setprio(0);
    }
  }

#pragma unroll
  for (int mi = 0; mi < MR; ++mi)
#pragma unroll
    for (int ni = 0; ni < 4; ++ni) {
      const int mb = m0 + wm * (MR * 16) + mi * 16 + l4 * 4;   // base t, mb&3 == 0
      const int n = n0 + wn * 64 + ni * 16 + l15;
      if constexpr (EPI == 0) {
        const int b = mb >> 11, tb = mb & 2047;
        const int which = n / (Hh * Dd);
        const int nn = n - which * (Hh * Dd);
        const int h = nn >> 6, d = nn & 63;
        if (which == 2) {
          // sigma-V^T direct: t' = swap bits 2<->3 of tb (tb&3==0), 4-run contiguous
          uint2 pw;
          pw.x = cvt_pk_bf16(acc[mi][ni][0], acc[mi][ni][1]);
          pw.y = cvt_pk_bf16(acc[mi][ni][2], acc[mi][ni][3]);
          const int tp = (tb & ~15) | ((tb & 4) << 1) | ((tb & 8) >> 1);
          *(uint2*)(vp + ((size_t)(b * Hh + h) * Dd + d) * Tt + tp) = pw;
        } else {
          u16* dst = (which == 0) ? qp : kp;
#pragma unroll
          for (int r = 0; r < 4; ++r)
            dst[((size_t)(b * Hh + h) * Tt + tb + r) * Dd + d] = f2bf(acc[mi][ni][r]);
        }
      } else if constexpr (EPI == 1) {
#pragma unroll
        for (int r = 0; r < 4; ++r) {
          float val = acc[mi][ni][r] + bias[n];
          val = fmaxf(val, 0.0f);
          out_u[(size_t)(mb + r) * Ndim + n] = f2bf(val);
        }
      } else {
#pragma unroll
        for (int r = 0; r < 4; ++r) {
          float val = acc[mi][ni][r];
          if (kz == 0) val += bias[n];
          out_p[(size_t)kz * Mdim * Ndim + (size_t)(mb + r) * Ndim + n] = f2bf(val);
        }
      }
    }
}

// ---------------- flash attention: 32x32 MFMA, in-register P, paired q-tiles ------
__global__ __launch_bounds__(256) void attn_kernel(const u16* __restrict__ q,
                                                   const u16* __restrict__ k,
                                                   const u16* __restrict__ vtg,
                                                   u16* __restrict__ Pb,
                                                   float* __restrict__ Lb) {
  __shared__ u16 kl[2][64 * 64];     // K tile [s][d], swizzled 128B rows
  __shared__ u16 vt[2][64 * 64];     // V^T tile [d][s'] sigma-permuted, swizzled
  const int tid = threadIdx.x, lane = tid & 63, w = tid >> 6;   // w 0..3
  const int l31 = lane & 31, hi = lane >> 5;
  const int bid = blockIdx.x;
  const int x8 = bid & 7, r3 = bid >> 3;
  const int g = r3 % 3, u = r3 / 3;          // u 0..39
  int q128, c, nt;
  if (u < 4)       { q128 = 15; c = u; nt = 8; }
  else if (u < 16) { const int v = u - 4;  q128 = 14 - v / 3; c = v % 3; nt = 8; }
  else if (u < 24) { const int v = u - 16; q128 = 10 - v / 2; c = v % 2; nt = 8; }
  else if (u < 28) { q128 = 6 - (u - 24); c = 0; nt = 8; }
  else             { const int v = u - 28; const int row = v >> 2, col = v & 3;
                     nt = 6 - 2 * row; q128 = 14 - row - 4 * col; c = 3 - col; }
  const int ts0 = c * 8;
  const int bh = g * 8 + x8;
  const int wq = 2 * q128 + (w >> 1);
  const int tg = q128 * 128 + (w >> 1) * 64 + (w & 1) * 32 + l31;
  constexpr float SC = 0.18033688f;          // log2(e)/8

  const u16* kgb = k + (size_t)bh * Tt * Dd;
  const u16* vgb = vtg + (size_t)bh * Dd * Tt;

  bf16x8 qf[4];
#pragma unroll
  for (int kt = 0; kt < 4; ++kt)
    qf[kt] = *(const bf16x8*)(q + ((size_t)bh * Tt + tg) * Dd + kt * 16 + hi * 8);

  {
    const int sb0 = ts0 * 64;
#pragma unroll
    for (int jj = 0; jj < 2; ++jj) {
      const int cb = (w * 2 + jj) * 64;
      const int ci = cb + lane;
      const int row = ci >> 3;
      const int sb = ((ci & 7) * 16) ^ ((row & 7) << 4);
      GLOAD_LDS16(kgb + (size_t)(sb0 + row) * Dd + (sb >> 1), kl[0] + (size_t)cb * 8);
      GLOAD_LDS16(vgb + (size_t)row * Tt + sb0 + (sb >> 1), vt[0] + (size_t)cb * 8);
    }
  }

  f32x16 oacc0 = {}, oacc1 = {};
  float lrun = 0.f;

  for (int jt = 0; jt < nt; ++jt) {
    __syncthreads();
    const int cur = jt & 1;
    if (jt + 1 < nt) {
      const int s0n = (ts0 + jt + 1) * 64;
#pragma unroll
      for (int jj = 0; jj < 2; ++jj) {
        const int cb = (w * 2 + jj) * 64;
        const int ci = cb + lane;
        const int row = ci >> 3;
        const int sb = ((ci & 7) * 16) ^ ((row & 7) << 4);
        GLOAD_LDS16(kgb + (size_t)(s0n + row) * Dd + (sb >> 1), kl[cur ^ 1] + (size_t)cb * 8);
        GLOAD_LDS16(vgb + (size_t)row * Tt + s0n + (sb >> 1), vt[cur ^ 1] + (size_t)cb * 8);
      }
    }
    const int tile = ts0 + jt;
    if (tile <= wq) {
      const u16* klc = kl[cur];
      const u16* vtc = vt[cur];

      f32x16 sacc0 = {}, sacc1 = {};
      __builtin_amdgcn_s_setprio(1);
#pragma unroll
      for (int kt = 0; kt < 4; ++kt) {
        const int b0 = kt * 32 + hi * 16;
        const bf16x8 kf0 = *(const bf16x8*)((const char*)klc + KSWZ(l31, b0));
        const bf16x8 kf1 = *(const bf16x8*)((const char*)klc + KSWZ(32 + l31, b0));
        sacc0 = mfma32(kf0, qf[kt], sacc0);
        sacc1 = mfma32(kf1, qf[kt], sacc1);
      }
      __builtin_amdgcn_s_setprio(0);

      const bool diag = (tile == wq);
      bf16x8 pf[4];
      float rs = 0.f;
#pragma unroll
      for (int sh = 0; sh < 2; ++sh) {
        const f32x16 sa = sh ? sacc1 : sacc0;
#pragma unroll
        for (int kt2 = 0; kt2 < 2; ++kt2) {
          float p8[8];
#pragma unroll
          for (int o = 0; o < 8; ++o) {
            const int r = kt2 * 8 + o;
            float e = __builtin_amdgcn_exp2f(sa[r] * SC);
            if (diag) {
              const int sg = tile * 64 + sh * 32 + kt2 * 16 + (o & 3) + 8 * (o >> 2) + 4 * hi;
              e = (sg > tg) ? 0.f : e;
            }
            p8[o] = e;
            rs += e;
          }
          uint4 uu;
          uu.x = cvt_pk_bf16(p8[0], p8[1]);
          uu.y = cvt_pk_bf16(p8[2], p8[3]);
          uu.z = cvt_pk_bf16(p8[4], p8[5]);
          uu.w = cvt_pk_bf16(p8[6], p8[7]);
          pf[sh * 2 + kt2] = __builtin_bit_cast(bf16x8, uu);
        }
      }
      lrun += rs;

      __builtin_amdgcn_s_setprio(1);
#pragma unroll
      for (int ks = 0; ks < 4; ++ks) {
        const int b0 = ks * 32 + hi * 16;
        const bf16x8 vf0 = *(const bf16x8*)((const char*)vtc + KSWZ(l31, b0));
        const bf16x8 vf1 = *(const bf16x8*)((const char*)vtc + KSWZ(32 + l31, b0));
        oacc0 = mfma32(vf0, pf[ks], oacc0);
        oacc1 = mfma32(vf1, pf[ks], oacc1);
      }
      __builtin_amdgcn_s_setprio(0);
    }
  }

  const float lt = lrun + __shfl_xor(lrun, 32);
  const int b = bh / Hh, h = bh - (bh / Hh) * Hh;
  u16* orow = Pb + (size_t)c * MROWS * Ee + ((size_t)b * Tt + tg) * Ee + h * Dd;
#pragma unroll
  for (int dt = 0; dt < 2; ++dt) {
    const f32x16 oa = dt ? oacc1 : oacc0;
#pragma unroll
    for (int kq = 0; kq < 4; ++kq) {
      uint2 pw;
      pw.x = cvt_pk_bf16(oa[4 * kq + 0], oa[4 * kq + 1]);
      pw.y = cvt_pk_bf16(oa[4 * kq + 2], oa[4 * kq + 3]);
      *(uint2*)(orow + dt * 32 + 8 * kq + 4 * hi) = pw;
    }
  }
  if (hi == 0)
    Lb[(size_t)c * MROWS * 12 + ((size_t)b * Tt + tg) * 12 + h] = lt;
}

// ---------------- LN1 (wave-per-row): combine bf16 partials + residual + LN -------
// grid MROWS/4 x 256; wave w owns row m = bid*4+w. No LDS, no barriers:
// 6-step shfl_xor reduce; per-head 1/l via lanes 0..11 + shfl broadcast.
__global__ __launch_bounds__(256) void ln1_kernel(const float* __restrict__ x,
                                                  const u16* __restrict__ P,
                                                  const float* __restrict__ L,
                                                  const float* __restrict__ g,
                                                  const float* __restrict__ beta,
                                                  u16* __restrict__ ybout) {
  const int w = threadIdx.x >> 6, lane = threadIdx.x & 63;
  const int m = blockIdx.x * 4 + w;
  const int t = m & (Tt - 1);
  float inv = 0.f;
  if (lane < 12) {
    float s = L[(size_t)m * 12 + lane];
    if (t >= 512)  s += L[(size_t)(1 * MROWS + m) * 12 + lane];
    if (t >= 1024) s += L[(size_t)(2 * MROWS + m) * 12 + lane];
    if (t >= 1536) s += L[(size_t)(3 * MROWS + m) * 12 + lane];
    inv = 1.0f / s;
  }
  float vbuf[12];
  float s = 0.f, ss = 0.f;
#pragma unroll
  for (int j = 0; j < 3; ++j) {
    const int e = j * 256 + lane * 4;
    const float ih = __shfl(inv, 4 * j + (lane >> 4));
    float o[4];
    {
      const uint2 p0 = *(const uint2*)(P + (size_t)m * Ee + e);
      const u16* pp = (const u16*)&p0;
#pragma unroll
      for (int r = 0; r < 4; ++r) o[r] = bf2f(pp[r]);
    }
    if (t >= 512) {
      const uint2 p1 = *(const uint2*)(P + (size_t)(1 * MROWS + m) * Ee + e);
      const u16* pp = (const u16*)&p1;
#pragma unroll
      for (int r = 0; r < 4; ++r) o[r] += bf2f(pp[r]);
    }
    if (t >= 1024) {
      const uint2 p2 = *(const uint2*)(P + (size_t)(2 * MROWS + m) * Ee + e);
      const u16* pp = (const u16*)&p2;
#pragma unroll
      for (int r = 0; r < 4; ++r) o[r] += bf2f(pp[r]);
    }
    if (t >= 1536) {
      const uint2 p3 = *(const uint2*)(P + (size_t)(3 * MROWS + m) * Ee + e);
      const u16* pp = (const u16*)&p3;
#pragma unroll
      for (int r = 0; r < 4; ++r) o[r] += bf2f(pp[r]);
    }
    const float4 xv = *(const float4*)(x + (size_t)m * Ee + e);
    const float xr[4] = {xv.x, xv.y, xv.z, xv.w};
#pragma unroll
    for (int r = 0; r < 4; ++r) {
      const float tv = xr[r] + o[r] * ih;
      vbuf[j * 4 + r] = tv;
      s += tv;
      ss += tv * tv;
    }
  }
#pragma unroll
  for (int off = 1; off < 64; off <<= 1) {
    s += __shfl_xor(s, off);
    ss += __shfl_xor(ss, off);
  }
  const float mu = s / Ee;
  const float var = ss / Ee - mu * mu;
  const float rinv = rsqrtf(var + 1e-5f);
#pragma unroll
  for (int j = 0; j < 3; ++j) {
    const int e = j * 256 + lane * 4;
    const float4 gv = *(const float4*)(g + e);
    const float4 bv = *(const float4*)(beta + e);
    const float t0 = (vbuf[j * 4 + 0] - mu) * rinv * gv.x + bv.x;
    const float t1 = (vbuf[j * 4 + 1] - mu) * rinv * gv.y + bv.y;
    const float t2 = (vbuf[j * 4 + 2] - mu) * rinv * gv.z + bv.z;
    const float t3 = (vbuf[j * 4 + 3] - mu) * rinv * gv.w + bv.w;
    uint2 pw;
    pw.x = cvt_pk_bf16(t0, t1);
    pw.y = cvt_pk_bf16(t2, t3);
    *(uint2*)(ybout + (size_t)m * Ee + e) = pw;
  }
}

// ---------------- LN2 (wave-per-row): bf16 residual + 2 bf16 partials + LN --------
__global__ __launch_bounds__(256) void ln2_kernel(const u16* __restrict__ a,
                                                  const u16* __restrict__ mlp,
                                                  const float* __restrict__ g,
                                                  const float* __restrict__ beta,
                                                  float* __restrict__ yout) {
  const int w = threadIdx.x >> 6, lane = threadIdx.x & 63;
  const int m = blockIdx.x * 4 + w;
  float vbuf[12];
  float s = 0.f, ss = 0.f;
#pragma unroll
  for (int j = 0; j < 3; ++j) {
    const int e = j * 256 + lane * 4;
    float o[4];
    {
      const uint2 p0 = *(const uint2*)(a + (size_t)m * Ee + e);
      const u16* pp = (const u16*)&p0;
#pragma unroll
      for (int r = 0; r < 4; ++r) o[r] = bf2f(pp[r]);
    }
#pragma unroll
    for (int kz = 0; kz < 2; ++kz) {
      const uint2 p1 = *(const uint2*)(mlp + (size_t)(kz * MROWS + m) * Ee + e);
      const u16* pp = (const u16*)&p1;
#pragma unroll
      for (int r = 0; r < 4; ++r) o[r] += bf2f(pp[r]);
    }
#pragma unroll
    for (int r = 0; r < 4; ++r) {
      vbuf[j * 4 + r] = o[r];
      s += o[r];
      ss += o[r] * o[r];
    }
  }
#pragma unroll
  for (int off = 1; off < 64; off <<= 1) {
    s += __shfl_xor(s, off);
    ss += __shfl_xor(ss, off);
  }
  const float mu = s / Ee;
  const float var = ss / Ee - mu * mu;
  const float rinv = rsqrtf(var + 1e-5f);
#pragma unroll
  for (int j = 0; j < 3; ++j) {
    const int e = j * 256 + lane * 4;
    const float4 gv = *(const float4*)(g + e);
    const float4 bv = *(const float4*)(beta + e);
    float4 ov;
    ov.x = (vbuf[j * 4 + 0] - mu) * rinv * gv.x + bv.x;
    ov.y = (vbuf[j * 4 + 1] - mu) * rinv * gv.y + bv.y;
    ov.z = (vbuf[j * 4 + 2] - mu) * rinv * gv.z + bv.z;
    ov.w = (vbuf[j * 4 + 3] - mu) * rinv * gv.w + bv.w;
    *(float4*)(yout + (size_t)m * Ee + e) = ov;
  }
}

// ---------------- launch ----------------
extern "C" void kernel_launch(void* const* d_in, const int* in_sizes, int n_in,
                              void* d_out, int out_size, void* d_ws, size_t ws_size,
                              hipStream_t stream) {
  const float* x  = (const float*)d_in[0];
  const float* Wq = (const float*)d_in[1];
  const float* Wk = (const float*)d_in[2];
  const float* Wv = (const float*)d_in[3];
  const float* W1 = (const float*)d_in[4];
  const float* b1 = (const float*)d_in[5];
  const float* W2 = (const float*)d_in[6];
  const float* b2 = (const float*)d_in[7];
  const float* g1 = (const float*)d_in[8];
  const float* be1 = (const float*)d_in[9];
  const float* g2 = (const float*)d_in[10];
  const float* be2 = (const float*)d_in[11];
  float* out = (float*)d_out;

  char* ws = (char*)d_ws;
  size_t off = 0;
  auto alloc = [&](size_t bytes) -> char* {
    char* p = ws + off;
    off += (bytes + 255) & ~(size_t)255;
    return p;
  };
  u16* xb    = (u16*)alloc((size_t)MROWS * Ee * 2);
  u16* wqkvt = (u16*)alloc((size_t)NQKV * Ee * 2);
  u16* w1t   = (u16*)alloc((size_t)HIDc * Ee * 2);
  u16* w2t   = (u16*)alloc((size_t)Ee * HIDc * 2);
  u16* qb    = (u16*)alloc((size_t)Bb * Hh * Tt * Dd * 2);
  u16* kb    = (u16*)alloc((size_t)Bb * Hh * Tt * Dd * 2);
  u16* vtb   = (u16*)alloc((size_t)Bb * Hh * Tt * Dd * 2);   // [B,H,D,T'] sigma
  u16* yb     = (u16*)alloc((size_t)MROWS * Ee * 2);
  float* Lb   = (float*)alloc((size_t)4 * MROWS * 12 * 4);
  // union slab: Pb bf16 (25.2MB, dead after ln1) | hbuf (25.2MB) + mlp 2x6.3MB bf16
  char* big = alloc((size_t)MROWS * HIDc * 2 + (size_t)2 * MROWS * Ee * 2);
  u16* Pb    = (u16*)big;
  u16* hbuf  = (u16*)big;
  u16* mlp   = (u16*)(big + (size_t)MROWS * HIDc * 2);
  (void)ws_size;

  // 1. fused prep (cvt_x + all weight transposes)
  prep_kernel<<<9408, 256, 0, stream>>>(x, xb, Wq, Wk, Wv, wqkvt, W1, w1t, W2, w2t);

  // 2. QKV projection (V written directly as sigma-V^T)
  gemm_bt_kernel<0, 64, 1><<<36 * 32, 256, 0, stream>>>(
      xb, wqkvt, nullptr, nullptr, nullptr, qb, kb, vtb, MROWS, NQKV, Ee, 36, 32);

  // 3. attention (paired q-tiles, chunked s, bf16 partial O + f32 l)
  attn_kernel<<<960, 256, 0, stream>>>(qb, kb, vtb, Pb, Lb);

  // 4. LN1 (combine partials + residual + LN) -> bf16 y, wave-per-row
  ln1_kernel<<<MROWS / 4, 256, 0, stream>>>(x, Pb, Lb, g1, be1, yb);

  // 5. MLP
  gemm_bt_kernel<1, 64, 1><<<48 * 32, 256, 0, stream>>>(
      yb, w1t, b1, hbuf, nullptr, nullptr, nullptr, nullptr, MROWS, HIDc, Ee, 48, 32);
  gemm_bt_kernel<2, 64, 2><<<12 * 32 * 2, 256, 0, stream>>>(
      hbuf, w2t, b2, nullptr, mlp, nullptr, nullptr, nullptr, MROWS, Ee, HIDc, 12, 32);

  // 6. LN2 (yb + 2 bf16 mlp partials) -> output, wave-per-row
  ln2_kernel<<<MROWS / 4, 256, 0, stream>>>(yb, mlp, g2, be2, out);
}

// Round 19
// 138.031 us; speedup vs baseline: 1.2758x; 1.0361x over previous
//
#include <hip/hip_runtime.h>
#include <stdint.h>

// Problem constants
constexpr int Ee   = 768;
constexpr int Hh   = 12;
constexpr int Dd   = 64;
constexpr int Tt   = 2048;
constexpr int Bb   = 2;
constexpr int HIDc = 3072;
constexpr int MROWS = Bb * Tt;        // 4096
constexpr int NQKV  = 3 * Hh * Dd;    // 2304

typedef unsigned short u16;
typedef __bf16 bf16;
typedef bf16 bf16x8 __attribute__((ext_vector_type(8)));
typedef float f32x4 __attribute__((ext_vector_type(4)));
typedef float f32x16 __attribute__((ext_vector_type(16)));

__device__ __forceinline__ u16 f2bf(float f) {
  uint32_t u = __builtin_bit_cast(uint32_t, f);
  u += 0x7fffu + ((u >> 16) & 1u);
  return (u16)(u >> 16);
}

__device__ __forceinline__ float bf2f(u16 v) {
  uint32_t u = (uint32_t)v << 16;
  return __builtin_bit_cast(float, u);
}

__device__ __forceinline__ uint32_t cvt_pk_bf16(float lo, float hi) {
  uint32_t r;
  asm("v_cvt_pk_bf16_f32 %0, %1, %2" : "=v"(r) : "v"(lo), "v"(hi));
  return r;
}

__device__ __forceinline__ f32x4 mfma16(bf16x8 a, bf16x8 b, f32x4 c) {
  return __builtin_amdgcn_mfma_f32_16x16x32_bf16(a, b, c, 0, 0, 0);
}

__device__ __forceinline__ f32x16 mfma32(bf16x8 a, bf16x8 b, f32x16 c) {
  return __builtin_amdgcn_mfma_f32_32x32x16_bf16(a, b, c, 0, 0, 0);
}

#define GLOAD_LDS16(gp, lp)                                                            \
  __builtin_amdgcn_global_load_lds((const __attribute__((address_space(1))) void*)(gp),\
                                   (__attribute__((address_space(3))) void*)(lp),      \
                                   16, 0, 0)

// XOR swizzle inside a 128-byte LDS row (T2, m201 pattern)
#define KSWZ(row, byte) ((row) * 128 + ((byte) ^ (((row) & 7) << 4)))

// ---------------- shared transpose body (32x32 f32 tile -> bf16 transposed) -------

__device__ __forceinline__ void tr_body(const float* __restrict__ ip,
                                        u16* __restrict__ op,
                                        int R, int C, int r0, int c0,
                                        float (*t)[33]) {
  const int tx = threadIdx.x & 31, ty = threadIdx.x >> 5;
#pragma unroll
  for (int i = 0; i < 4; ++i)
    t[ty * 4 + i][tx] = ip[(size_t)(r0 + ty * 4 + i) * C + c0 + tx];
  __syncthreads();
#pragma unroll
  for (int i = 0; i < 4; ++i)
    op[(size_t)(c0 + ty * 4 + i) * R + r0 + tx] = f2bf(t[tx][ty * 4 + i]);
}

// ---------------- prep: cvt_x + tr_qkv only (W1/W2 transposes moved to attn) ------
__global__ __launch_bounds__(256) void prep_kernel(
    const float* __restrict__ x, u16* __restrict__ xb,
    const float* __restrict__ Wq, const float* __restrict__ Wk,
    const float* __restrict__ Wv, u16* __restrict__ wqkvt) {
  __shared__ float t[32][33];
  int bid = blockIdx.x;
  if (bid < 3072) {                 // cvt_x
    const int i = bid * 256 + threadIdx.x;
    const float4 f = *(const float4*)(x + (size_t)i * 4);
    uint2 o;
    u16* po = (u16*)&o;
    po[0] = f2bf(f.x); po[1] = f2bf(f.y); po[2] = f2bf(f.z); po[3] = f2bf(f.w);
    *(uint2*)(xb + (size_t)i * 4) = o;
    return;
  }
  bid -= 3072;
  {                                 // tr_qkv: bx(2) x by(24) x z(36)
    const int bx = bid & 1;
    const int rest = bid >> 1;
    const int by = rest % 24, z = rest / 24;
    const int which = z / 12, hs = z - which * 12;
    const float* W = (which == 0) ? Wq : (which == 1) ? Wk : Wv;
    tr_body(W + (size_t)hs * Ee * Dd, wqkvt + ((size_t)which * 768 + hs * 64) * Ee,
            Ee, Dd, by * 32, bx * 32, t);
  }
}

// ---------------- GEMM: C[M,N] = A[M,K](bf16) * Bt[N,K](bf16)^T ----------------
// r14 measured-best config: BN=64, BK=64, double-buffered, __syncthreads-based.
template <int EPI, int BN, int SPLITK>
__global__ __launch_bounds__(256) void gemm_bt_kernel(
    const u16* __restrict__ A, const u16* __restrict__ Bt,
    const float* __restrict__ bias,
    u16* __restrict__ out_u, u16* __restrict__ out_p,
    u16* __restrict__ qp, u16* __restrict__ kp, u16* __restrict__ vp,
    int Mdim, int Ndim, int Kdim, int gx, int gy) {
  constexpr int WN = BN / 64;          // 1
  constexpr int WM = 4 / WN;           // 4
  constexpr int MR = 128 / WM / 16;    // 2
  constexpr int ACH = 16;
  constexpr int BCH = BN / 8;          // 8
  __shared__ u16 la[2][128 * 64];
  __shared__ u16 lb[2][BN * 64];
  const int tid = threadIdx.x, lane = tid & 63, wv = tid >> 6;
  const int wm = wv / WN, wn = wv % WN;
  const int l15 = lane & 15, l4 = lane >> 4;

  const int nwg = gx * gy * SPLITK;
  const int cpx = nwg >> 3;
  const int wg = (blockIdx.x & 7) * cpx + (blockIdx.x >> 3);
  const int bx = wg % gx;
  const int byz = wg / gx;
  const int by = byz % gy;
  const int kz = byz / gy;
  const int m0 = by * 128, n0 = bx * BN;
  const int Ks = Kdim / SPLITK;
  const int kbase = kz * Ks;
  const int niter = Ks / 64;

  auto stage = [&](int it, int buf) {
    const int k0 = kbase + it * 64;
#pragma unroll
    for (int j = 0; j < ACH / 4; ++j) {
      const int cb = (wv * (ACH / 4) + j) * 64;
      const int ci = cb + lane;
      const int row = ci >> 3;
      const int kbl = ((ci & 7) * 16) ^ ((row & 7) << 4);
      GLOAD_LDS16(A + (size_t)(m0 + row) * Kdim + k0 + (kbl >> 1), la[buf] + (size_t)cb * 8);
    }
#pragma unroll
    for (int j = 0; j < BCH / 4; ++j) {
      const int cb = (wv * (BCH / 4) + j) * 64;
      const int ci = cb + lane;
      const int row = ci >> 3;
      const int kbl = ((ci & 7) * 16) ^ ((row & 7) << 4);
      GLOAD_LDS16(Bt + (size_t)(n0 + row) * Kdim + k0 + (kbl >> 1), lb[buf] + (size_t)cb * 8);
    }
  };

  f32x4 acc[MR][4] = {};
  stage(0, 0);

  for (int it = 0; it < niter; ++it) {
    __syncthreads();                 // tile it landed; buf[it^1] readers done
    const int cur = it & 1;
    if (it + 1 < niter) stage(it + 1, cur ^ 1);
    const char* lac = (const char*)la[cur];
    const char* lbc = (const char*)lb[cur];
#pragma unroll
    for (int ks = 0; ks < 2; ++ks) {
      bf16x8 af[MR], bfr[4];
#pragma unroll
      for (int i = 0; i < MR; ++i) {
        const int row = wm * (MR * 16) + i * 16 + l15;
        af[i] = *(const bf16x8*)(lac + row * 128 +
                                 (((ks * 64 + l4 * 16)) ^ ((row & 7) << 4)));
      }
#pragma unroll
      for (int i = 0; i < 4; ++i) {
        const int row = wn * 64 + i * 16 + l15;
        bfr[i] = *(const bf16x8*)(lbc + row * 128 +
                                  (((ks * 64 + l4 * 16)) ^ ((row & 7) << 4)));
      }
      __builtin_amdgcn_s_setprio(1);
#pragma unroll
      for (int mi = 0; mi < MR; ++mi)
#pragma unroll
        for (int ni = 0; ni < 4; ++ni)
          acc[mi][ni] = mfma16(af[mi], bfr[ni], acc[mi][ni]);
      __builtin_amdgcn_s_setprio(0);
    }
  }

#pragma unroll
  for (int mi = 0; mi < MR; ++mi)
#pragma unroll
    for (int ni = 0; ni < 4; ++ni) {
      const int mb = m0 + wm * (MR * 16) + mi * 16 + l4 * 4;   // base t, mb&3 == 0
      const int n = n0 + wn * 64 + ni * 16 + l15;
      if constexpr (EPI == 0) {
        const int b = mb >> 11, tb = mb & 2047;
        const int which = n / (Hh * Dd);
        const int nn = n - which * (Hh * Dd);
        const int h = nn >> 6, d = nn & 63;
        if (which == 2) {
          // sigma-V^T direct: t' = swap bits 2<->3 of tb (tb&3==0), 4-run contiguous
          uint2 pw;
          pw.x = cvt_pk_bf16(acc[mi][ni][0], acc[mi][ni][1]);
          pw.y = cvt_pk_bf16(acc[mi][ni][2], acc[mi][ni][3]);
          const int tp = (tb & ~15) | ((tb & 4) << 1) | ((tb & 8) >> 1);
          *(uint2*)(vp + ((size_t)(b * Hh + h) * Dd + d) * Tt + tp) = pw;
        } else {
          u16* dst = (which == 0) ? qp : kp;
#pragma unroll
          for (int r = 0; r < 4; ++r)
            dst[((size_t)(b * Hh + h) * Tt + tb + r) * Dd + d] = f2bf(acc[mi][ni][r]);
        }
      } else if constexpr (EPI == 1) {
#pragma unroll
        for (int r = 0; r < 4; ++r) {
          float val = acc[mi][ni][r] + bias[n];
          val = fmaxf(val, 0.0f);
          out_u[(size_t)(mb + r) * Ndim + n] = f2bf(val);
        }
      } else {
#pragma unroll
        for (int r = 0; r < 4; ++r) {
          float val = acc[mi][ni][r];
          if (kz == 0) val += bias[n];
          out_p[(size_t)kz * Mdim * Ndim + (size_t)(mb + r) * Ndim + n] = f2bf(val);
        }
      }
    }
}

// ---------------- flash attention + overlapped W1/W2 transposes -------------------
// Blocks [0,960): attention (paired q-tiles, chunked s, bf16 partial O + f32 l).
// Blocks [960,5568): W1/W2 tiled transposes (BW-bound, overlap attention's
// MFMA/latency-bound phase; complete before gemm2). LDS for the 32x33 f32
// tile aliases the attention K buffer (branch is block-uniform).
__global__ __launch_bounds__(256) void attn_kernel(const u16* __restrict__ q,
                                                   const u16* __restrict__ k,
                                                   const u16* __restrict__ vtg,
                                                   u16* __restrict__ Pb,
                                                   float* __restrict__ Lb,
                                                   const float* __restrict__ W1,
                                                   u16* __restrict__ w1t,
                                                   const float* __restrict__ W2,
                                                   u16* __restrict__ w2t) {
  __shared__ u16 kl[2][64 * 64];     // K tile [s][d], swizzled 128B rows
  __shared__ u16 vt[2][64 * 64];     // V^T tile [d][s'] sigma-permuted, swizzled
  const int bid = blockIdx.x;
  if (bid >= 960) {                  // overlapped weight transposes
    float (*tt)[33] = (float(*)[33])kl;
    int b2 = bid - 960;
    if (b2 < 2304) {                 // W1 [768][3072] -> w1t [3072][768]
      const int bx = b2 % 96, by = b2 / 96;
      tr_body(W1, w1t, Ee, HIDc, by * 32, bx * 32, tt);
    } else {                         // W2 [3072][768] -> w2t [768][3072]
      b2 -= 2304;
      const int bx = b2 % 24, by = b2 / 24;
      tr_body(W2, w2t, HIDc, Ee, by * 32, bx * 32, tt);
    }
    return;
  }
  const int tid = threadIdx.x, lane = tid & 63, w = tid >> 6;   // w 0..3
  const int l31 = lane & 31, hi = lane >> 5;
  const int x8 = bid & 7, r3 = bid >> 3;
  const int g = r3 % 3, u = r3 / 3;          // u 0..39
  int q128, c, nt;
  if (u < 4)       { q128 = 15; c = u; nt = 8; }
  else if (u < 16) { const int v = u - 4;  q128 = 14 - v / 3; c = v % 3; nt = 8; }
  else if (u < 24) { const int v = u - 16; q128 = 10 - v / 2; c = v % 2; nt = 8; }
  else if (u < 28) { q128 = 6 - (u - 24); c = 0; nt = 8; }
  else             { const int v = u - 28; const int row = v >> 2, col = v & 3;
                     nt = 6 - 2 * row; q128 = 14 - row - 4 * col; c = 3 - col; }
  const int ts0 = c * 8;
  const int bh = g * 8 + x8;
  const int wq = 2 * q128 + (w >> 1);
  const int tg = q128 * 128 + (w >> 1) * 64 + (w & 1) * 32 + l31;
  constexpr float SC = 0.18033688f;          // log2(e)/8

  const u16* kgb = k + (size_t)bh * Tt * Dd;
  const u16* vgb = vtg + (size_t)bh * Dd * Tt;

  bf16x8 qf[4];
#pragma unroll
  for (int kt = 0; kt < 4; ++kt)
    qf[kt] = *(const bf16x8*)(q + ((size_t)bh * Tt + tg) * Dd + kt * 16 + hi * 8);

  {
    const int sb0 = ts0 * 64;
#pragma unroll
    for (int jj = 0; jj < 2; ++jj) {
      const int cb = (w * 2 + jj) * 64;
      const int ci = cb + lane;
      const int row = ci >> 3;
      const int sb = ((ci & 7) * 16) ^ ((row & 7) << 4);
      GLOAD_LDS16(kgb + (size_t)(sb0 + row) * Dd + (sb >> 1), kl[0] + (size_t)cb * 8);
      GLOAD_LDS16(vgb + (size_t)row * Tt + sb0 + (sb >> 1), vt[0] + (size_t)cb * 8);
    }
  }

  f32x16 oacc0 = {}, oacc1 = {};
  float lrun = 0.f;

  for (int jt = 0; jt < nt; ++jt) {
    __syncthreads();
    const int cur = jt & 1;
    if (jt + 1 < nt) {
      const int s0n = (ts0 + jt + 1) * 64;
#pragma unroll
      for (int jj = 0; jj < 2; ++jj) {
        const int cb = (w * 2 + jj) * 64;
        const int ci = cb + lane;
        const int row = ci >> 3;
        const int sb = ((ci & 7) * 16) ^ ((row & 7) << 4);
        GLOAD_LDS16(kgb + (size_t)(s0n + row) * Dd + (sb >> 1), kl[cur ^ 1] + (size_t)cb * 8);
        GLOAD_LDS16(vgb + (size_t)row * Tt + s0n + (sb >> 1), vt[cur ^ 1] + (size_t)cb * 8);
      }
    }
    const int tile = ts0 + jt;
    if (tile <= wq) {
      const u16* klc = kl[cur];
      const u16* vtc = vt[cur];

      f32x16 sacc0 = {}, sacc1 = {};
      __builtin_amdgcn_s_setprio(1);
#pragma unroll
      for (int kt = 0; kt < 4; ++kt) {
        const int b0 = kt * 32 + hi * 16;
        const bf16x8 kf0 = *(const bf16x8*)((const char*)klc + KSWZ(l31, b0));
        const bf16x8 kf1 = *(const bf16x8*)((const char*)klc + KSWZ(32 + l31, b0));
        sacc0 = mfma32(kf0, qf[kt], sacc0);
        sacc1 = mfma32(kf1, qf[kt], sacc1);
      }
      __builtin_amdgcn_s_setprio(0);

      const bool diag = (tile == wq);
      bf16x8 pf[4];
      float rs = 0.f;
#pragma unroll
      for (int sh = 0; sh < 2; ++sh) {
        const f32x16 sa = sh ? sacc1 : sacc0;
#pragma unroll
        for (int kt2 = 0; kt2 < 2; ++kt2) {
          float p8[8];
#pragma unroll
          for (int o = 0; o < 8; ++o) {
            const int r = kt2 * 8 + o;
            float e = __builtin_amdgcn_exp2f(sa[r] * SC);
            if (diag) {
              const int sg = tile * 64 + sh * 32 + kt2 * 16 + (o & 3) + 8 * (o >> 2) + 4 * hi;
              e = (sg > tg) ? 0.f : e;
            }
            p8[o] = e;
            rs += e;
          }
          uint4 uu;
          uu.x = cvt_pk_bf16(p8[0], p8[1]);
          uu.y = cvt_pk_bf16(p8[2], p8[3]);
          uu.z = cvt_pk_bf16(p8[4], p8[5]);
          uu.w = cvt_pk_bf16(p8[6], p8[7]);
          pf[sh * 2 + kt2] = __builtin_bit_cast(bf16x8, uu);
        }
      }
      lrun += rs;

      __builtin_amdgcn_s_setprio(1);
#pragma unroll
      for (int ks = 0; ks < 4; ++ks) {
        const int b0 = ks * 32 + hi * 16;
        const bf16x8 vf0 = *(const bf16x8*)((const char*)vtc + KSWZ(l31, b0));
        const bf16x8 vf1 = *(const bf16x8*)((const char*)vtc + KSWZ(32 + l31, b0));
        oacc0 = mfma32(vf0, pf[ks], oacc0);
        oacc1 = mfma32(vf1, pf[ks], oacc1);
      }
      __builtin_amdgcn_s_setprio(0);
    }
  }

  const float lt = lrun + __shfl_xor(lrun, 32);
  const int b = bh / Hh, h = bh - (bh / Hh) * Hh;
  u16* orow = Pb + (size_t)c * MROWS * Ee + ((size_t)b * Tt + tg) * Ee + h * Dd;
#pragma unroll
  for (int dt = 0; dt < 2; ++dt) {
    const f32x16 oa = dt ? oacc1 : oacc0;
#pragma unroll
    for (int kq = 0; kq < 4; ++kq) {
      uint2 pw;
      pw.x = cvt_pk_bf16(oa[4 * kq + 0], oa[4 * kq + 1]);
      pw.y = cvt_pk_bf16(oa[4 * kq + 2], oa[4 * kq + 3]);
      *(uint2*)(orow + dt * 32 + 8 * kq + 4 * hi) = pw;
    }
  }
  if (hi == 0)
    Lb[(size_t)c * MROWS * 12 + ((size_t)b * Tt + tg) * 12 + h] = lt;
}

// ---------------- LN1 (wave-per-row): combine bf16 partials + bf16 residual + LN --
__global__ __launch_bounds__(256) void ln1_kernel(const u16* __restrict__ xb,
                                                  const u16* __restrict__ P,
                                                  const float* __restrict__ L,
                                                  const float* __restrict__ g,
                                                  const float* __restrict__ beta,
                                                  u16* __restrict__ ybout) {
  const int w = threadIdx.x >> 6, lane = threadIdx.x & 63;
  const int m = blockIdx.x * 4 + w;
  const int t = m & (Tt - 1);
  float inv = 0.f;
  if (lane < 12) {
    float s = L[(size_t)m * 12 + lane];
    if (t >= 512)  s += L[(size_t)(1 * MROWS + m) * 12 + lane];
    if (t >= 1024) s += L[(size_t)(2 * MROWS + m) * 12 + lane];
    if (t >= 1536) s += L[(size_t)(3 * MROWS + m) * 12 + lane];
    inv = 1.0f / s;
  }
  float vbuf[12];
  float s = 0.f, ss = 0.f;
#pragma unroll
  for (int j = 0; j < 3; ++j) {
    const int e = j * 256 + lane * 4;
    const float ih = __shfl(inv, 4 * j + (lane >> 4));
    float o[4];
    {
      const uint2 p0 = *(const uint2*)(P + (size_t)m * Ee + e);
      const u16* pp = (const u16*)&p0;
#pragma unroll
      for (int r = 0; r < 4; ++r) o[r] = bf2f(pp[r]);
    }
    if (t >= 512) {
      const uint2 p1 = *(const uint2*)(P + (size_t)(1 * MROWS + m) * Ee + e);
      const u16* pp = (const u16*)&p1;
#pragma unroll
      for (int r = 0; r < 4; ++r) o[r] += bf2f(pp[r]);
    }
    if (t >= 1024) {
      const uint2 p2 = *(const uint2*)(P + (size_t)(2 * MROWS + m) * Ee + e);
      const u16* pp = (const u16*)&p2;
#pragma unroll
      for (int r = 0; r < 4; ++r) o[r] += bf2f(pp[r]);
    }
    if (t >= 1536) {
      const uint2 p3 = *(const uint2*)(P + (size_t)(3 * MROWS + m) * Ee + e);
      const u16* pp = (const u16*)&p3;
#pragma unroll
      for (int r = 0; r < 4; ++r) o[r] += bf2f(pp[r]);
    }
    const uint2 xv = *(const uint2*)(xb + (size_t)m * Ee + e);
    const u16* xp = (const u16*)&xv;
#pragma unroll
    for (int r = 0; r < 4; ++r) {
      const float tv = bf2f(xp[r]) + o[r] * ih;
      vbuf[j * 4 + r] = tv;
      s += tv;
      ss += tv * tv;
    }
  }
#pragma unroll
  for (int off = 1; off < 64; off <<= 1) {
    s += __shfl_xor(s, off);
    ss += __shfl_xor(ss, off);
  }
  const float mu = s / Ee;
  const float var = ss / Ee - mu * mu;
  const float rinv = rsqrtf(var + 1e-5f);
#pragma unroll
  for (int j = 0; j < 3; ++j) {
    const int e = j * 256 + lane * 4;
    const float4 gv = *(const float4*)(g + e);
    const float4 bv = *(const float4*)(beta + e);
    const float t0 = (vbuf[j * 4 + 0] - mu) * rinv * gv.x + bv.x;
    const float t1 = (vbuf[j * 4 + 1] - mu) * rinv * gv.y + bv.y;
    const float t2 = (vbuf[j * 4 + 2] - mu) * rinv * gv.z + bv.z;
    const float t3 = (vbuf[j * 4 + 3] - mu) * rinv * gv.w + bv.w;
    uint2 pw;
    pw.x = cvt_pk_bf16(t0, t1);
    pw.y = cvt_pk_bf16(t2, t3);
    *(uint2*)(ybout + (size_t)m * Ee + e) = pw;
  }
}

// ---------------- LN2 (wave-per-row): bf16 residual + 2 bf16 partials + LN --------
__global__ __launch_bounds__(256) void ln2_kernel(const u16* __restrict__ a,
                                                  const u16* __restrict__ mlp,
                                                  const float* __restrict__ g,
                                                  const float* __restrict__ beta,
                                                  float* __restrict__ yout) {
  const int w = threadIdx.x >> 6, lane = threadIdx.x & 63;
  const int m = blockIdx.x * 4 + w;
  float vbuf[12];
  float s = 0.f, ss = 0.f;
#pragma unroll
  for (int j = 0; j < 3; ++j) {
    const int e = j * 256 + lane * 4;
    float o[4];
    {
      const uint2 p0 = *(const uint2*)(a + (size_t)m * Ee + e);
      const u16* pp = (const u16*)&p0;
#pragma unroll
      for (int r = 0; r < 4; ++r) o[r] = bf2f(pp[r]);
    }
#pragma unroll
    for (int kz = 0; kz < 2; ++kz) {
      const uint2 p1 = *(const uint2*)(mlp + (size_t)(kz * MROWS + m) * Ee + e);
      const u16* pp = (const u16*)&p1;
#pragma unroll
      for (int r = 0; r < 4; ++r) o[r] += bf2f(pp[r]);
    }
#pragma unroll
    for (int r = 0; r < 4; ++r) {
      vbuf[j * 4 + r] = o[r];
      s += o[r];
      ss += o[r] * o[r];
    }
  }
#pragma unroll
  for (int off = 1; off < 64; off <<= 1) {
    s += __shfl_xor(s, off);
    ss += __shfl_xor(ss, off);
  }
  const float mu = s / Ee;
  const float var = ss / Ee - mu * mu;
  const float rinv = rsqrtf(var + 1e-5f);
#pragma unroll
  for (int j = 0; j < 3; ++j) {
    const int e = j * 256 + lane * 4;
    const float4 gv = *(const float4*)(g + e);
    const float4 bv = *(const float4*)(beta + e);
    float4 ov;
    ov.x = (vbuf[j * 4 + 0] - mu) * rinv * gv.x + bv.x;
    ov.y = (vbuf[j * 4 + 1] - mu) * rinv * gv.y + bv.y;
    ov.z = (vbuf[j * 4 + 2] - mu) * rinv * gv.z + bv.z;
    ov.w = (vbuf[j * 4 + 3] - mu) * rinv * gv.w + bv.w;
    *(float4*)(yout + (size_t)m * Ee + e) = ov;
  }
}

// ---------------- launch ----------------
extern "C" void kernel_launch(void* const* d_in, const int* in_sizes, int n_in,
                              void* d_out, int out_size, void* d_ws, size_t ws_size,
                              hipStream_t stream) {
  const float* x  = (const float*)d_in[0];
  const float* Wq = (const float*)d_in[1];
  const float* Wk = (const float*)d_in[2];
  const float* Wv = (const float*)d_in[3];
  const float* W1 = (const float*)d_in[4];
  const float* b1 = (const float*)d_in[5];
  const float* W2 = (const float*)d_in[6];
  const float* b2 = (const float*)d_in[7];
  const float* g1 = (const float*)d_in[8];
  const float* be1 = (const float*)d_in[9];
  const float* g2 = (const float*)d_in[10];
  const float* be2 = (const float*)d_in[11];
  float* out = (float*)d_out;

  char* ws = (char*)d_ws;
  size_t off = 0;
  auto alloc = [&](size_t bytes) -> char* {
    char* p = ws + off;
    off += (bytes + 255) & ~(size_t)255;
    return p;
  };
  u16* xb    = (u16*)alloc((size_t)MROWS * Ee * 2);
  u16* wqkvt = (u16*)alloc((size_t)NQKV * Ee * 2);
  u16* w1t   = (u16*)alloc((size_t)HIDc * Ee * 2);
  u16* w2t   = (u16*)alloc((size_t)Ee * HIDc * 2);
  u16* qb    = (u16*)alloc((size_t)Bb * Hh * Tt * Dd * 2);
  u16* kb    = (u16*)alloc((size_t)Bb * Hh * Tt * Dd * 2);
  u16* vtb   = (u16*)alloc((size_t)Bb * Hh * Tt * Dd * 2);   // [B,H,D,T'] sigma
  u16* yb     = (u16*)alloc((size_t)MROWS * Ee * 2);
  float* Lb   = (float*)alloc((size_t)4 * MROWS * 12 * 4);
  // union slab: Pb bf16 (25.2MB, dead after ln1) | hbuf (25.2MB) + mlp 2x6.3MB bf16
  char* big = alloc((size_t)MROWS * HIDc * 2 + (size_t)2 * MROWS * Ee * 2);
  u16* Pb    = (u16*)big;
  u16* hbuf  = (u16*)big;
  u16* mlp   = (u16*)(big + (size_t)MROWS * HIDc * 2);
  (void)ws_size;

  // 1. prep (cvt_x + qkv weight transposes only)
  prep_kernel<<<4800, 256, 0, stream>>>(x, xb, Wq, Wk, Wv, wqkvt);

  // 2. QKV projection (V written directly as sigma-V^T)
  gemm_bt_kernel<0, 64, 1><<<36 * 32, 256, 0, stream>>>(
      xb, wqkvt, nullptr, nullptr, nullptr, qb, kb, vtb, MROWS, NQKV, Ee, 36, 32);

  // 3. attention + overlapped W1/W2 transposes
  attn_kernel<<<960 + 4608, 256, 0, stream>>>(qb, kb, vtb, Pb, Lb, W1, w1t, W2, w2t);

  // 4. LN1 (combine partials + bf16 residual + LN) -> bf16 y, wave-per-row
  ln1_kernel<<<MROWS / 4, 256, 0, stream>>>(xb, Pb, Lb, g1, be1, yb);

  // 5. MLP
  gemm_bt_kernel<1, 64, 1><<<48 * 32, 256, 0, stream>>>(
      yb, w1t, b1, hbuf, nullptr, nullptr, nullptr, nullptr, MROWS, HIDc, Ee, 48, 32);
  gemm_bt_kernel<2, 64, 2><<<12 * 32 * 2, 256, 0, stream>>>(
      hbuf, w2t, b2, nullptr, mlp, nullptr, nullptr, nullptr, MROWS, Ee, HIDc, 12, 32);

  // 6. LN2 (yb + 2 bf16 mlp partials) -> output, wave-per-row
  ln2_kernel<<<MROWS / 4, 256, 0, stream>>>(yb, mlp, g2, be2, out);
}